// Round 1
// baseline (449.994 us; speedup 1.0000x reference)
//
#include <hip/hip_runtime.h>

typedef _Float16 f16;
typedef __attribute__((ext_vector_type(4))) _Float16 f16x4;
typedef __attribute__((ext_vector_type(8))) _Float16 f16x8;
typedef __attribute__((ext_vector_type(4))) float f32x4;

#define NB 4
#define NS 2048
#define NE 1024
#define NH 16
#define ND 64
#define NM (NB*NS)   // 8192 tokens

__device__ __forceinline__ void gld16(const void* g, void* l) {
  __builtin_amdgcn_global_load_lds((const __attribute__((address_space(1))) unsigned int*)g,
                                   (__attribute__((address_space(3))) unsigned int*)l, 16, 0, 0);
}

// ---------------- f32 -> f16 convert ----------------
__global__ __launch_bounds__(256) void cvt_kernel(const float* __restrict__ in,
                                                  f16* __restrict__ out, int n4) {
  int idx = blockIdx.x * blockDim.x + threadIdx.x;
  int stride = gridDim.x * blockDim.x;
  for (int i = idx; i < n4; i += stride) {
    float4 v = ((const float4*)in)[i];
    f16x4 o;
    o[0] = (_Float16)v.x; o[1] = (_Float16)v.y; o[2] = (_Float16)v.z; o[3] = (_Float16)v.w;
    ((f16x4*)out)[i] = o;
  }
}

// ---------------- NT GEMM: C = A[M,K] * B[N,K]^T + bias ----------------
// m97 structure: 128x128 tile, BK=32, 4 waves (2x2), global_load_lds width 16.
template<bool OUTF32>
__global__ __launch_bounds__(256)
void gemm_bt(const f16* __restrict__ A, const f16* __restrict__ Bw,
             const float* __restrict__ bias, float* __restrict__ Cf,
             f16* __restrict__ Ch, int M, int N, int K)
{
  __shared__ __align__(16) f16 As[128*32];
  __shared__ __align__(16) f16 Bs[128*32];
  const int t = threadIdx.x;
  const int l = t & 63, w = t >> 6;
  const int wr = w >> 1, wc = w & 1;
  const int m0 = blockIdx.y * 128, n0 = blockIdx.x * 128;

  f32x4 acc[4][4];
  #pragma unroll
  for (int i = 0; i < 4; ++i)
    #pragma unroll
    for (int j = 0; j < 4; ++j)
      acc[i][j] = f32x4{0.f, 0.f, 0.f, 0.f};

  // staging: 8KB per tile = 256 threads x 2 chunks x 16B; LDS layout [row][k] f16
  const int off0 = (w*2+0)*1024 + l*16;       // byte offset in 8KB tile
  const int off1 = (w*2+1)*1024 + l*16;
  const int row0 = off0 >> 6, k0 = (off0 & 63) >> 1;
  const int row1 = off1 >> 6, k1 = (off1 & 63) >> 1;
  const f16* a0 = A  + (size_t)(m0+row0)*K + k0;
  const f16* a1 = A  + (size_t)(m0+row1)*K + k1;
  const f16* b0 = Bw + (size_t)(n0+row0)*K + k0;
  const f16* b1 = Bw + (size_t)(n0+row1)*K + k1;
  f16* As0 = As + off0/2; f16* As1 = As + off1/2;
  f16* Bs0 = Bs + off0/2; f16* Bs1 = Bs + off1/2;

  const int aoff = (wr*64 + (l&15))*32 + ((l>>4)<<3);
  const int boff = (wc*64 + (l&15))*32 + ((l>>4)<<3);

  for (int kt = 0; kt < K; kt += 32) {
    __syncthreads();
    gld16(a0 + kt, As0);
    gld16(a1 + kt, As1);
    gld16(b0 + kt, Bs0);
    gld16(b1 + kt, Bs1);
    __syncthreads();   // compiler drains vmcnt(0) before barrier
    f16x8 af[4], bf[4];
    #pragma unroll
    for (int i = 0; i < 4; ++i) af[i] = *(const f16x8*)(As + aoff + i*512);
    #pragma unroll
    for (int j = 0; j < 4; ++j) bf[j] = *(const f16x8*)(Bs + boff + j*512);
    #pragma unroll
    for (int i = 0; i < 4; ++i)
      #pragma unroll
      for (int j = 0; j < 4; ++j)
        acc[i][j] = __builtin_amdgcn_mfma_f32_16x16x32_f16(af[i], bf[j], acc[i][j], 0, 0, 0);
  }

  #pragma unroll
  for (int j = 0; j < 4; ++j) {
    const int col = n0 + wc*64 + j*16 + (l & 15);
    const float bb = bias[col];
    #pragma unroll
    for (int i = 0; i < 4; ++i) {
      const int rowb = m0 + wr*64 + i*16 + ((l>>4)<<2);
      #pragma unroll
      for (int r = 0; r < 4; ++r) {
        float v = acc[i][j][r] + bb;
        if constexpr (OUTF32) Cf[(size_t)(rowb+r)*N + col] = v;
        else                  Ch[(size_t)(rowb+r)*N + col] = (f16)v;
      }
    }
  }
}

// ---------------- flash attention ----------------
// grid: (16 q-tiles, 64 b*h), 256 threads = 4 waves, each wave owns 32 q-rows.
// K-tile = 64 keys. K_lds[64][72], Vt_lds[64][72] (transposed), Ps per-wave [32][72].
__global__ __launch_bounds__(256)
void attn_kernel(const f16* __restrict__ Q, const f16* __restrict__ K,
                 const f16* __restrict__ V, f16* __restrict__ O)
{
  __shared__ __align__(16) f16 Ks[64*72];
  __shared__ __align__(16) f16 Vt[64*72];
  __shared__ __align__(16) f16 Ps[4][32*72];

  const int t = threadIdx.x, l = t & 63, w = t >> 6;
  const int qt = blockIdx.x;       // 0..15
  const int bh = blockIdx.y;       // 0..63
  const int b = bh >> 4, h = bh & 15;
  const size_t base = (size_t)b * NS * NE + (size_t)h * ND;
  const int q0 = qt*128 + w*32;

  // Q fragments, held in registers for the whole block
  f16x8 aq[2][2];
  #pragma unroll
  for (int rg = 0; rg < 2; ++rg)
    #pragma unroll
    for (int kf = 0; kf < 2; ++kf)
      aq[rg][kf] = *(const f16x8*)&Q[base + (size_t)(q0 + rg*16 + (l&15))*NE + kf*32 + ((l>>4)<<3)];

  f32x4 o[2][4];
  #pragma unroll
  for (int rg = 0; rg < 2; ++rg)
    #pragma unroll
    for (int df = 0; df < 4; ++df) o[rg][df] = f32x4{0.f, 0.f, 0.f, 0.f};
  float mrow[2][4], lrow[2][4];
  #pragma unroll
  for (int rg = 0; rg < 2; ++rg)
    #pragma unroll
    for (int r = 0; r < 4; ++r) { mrow[rg][r] = -1e30f; lrow[rg][r] = 0.f; }

  const int sj = t >> 2;            // staging row 0..63
  const int sc = (t & 3) * 16;      // staging d-base 0,16,32,48

  for (int j0 = 0; j0 < NS; j0 += 64) {
    __syncthreads();
    {
      const f16* ksrc = &K[base + (size_t)(j0 + sj)*NE + sc];
      f16x8 kv0 = *(const f16x8*)ksrc;
      f16x8 kv1 = *(const f16x8*)(ksrc + 8);
      *(f16x8*)&Ks[sj*72 + sc]     = kv0;
      *(f16x8*)&Ks[sj*72 + sc + 8] = kv1;
      const f16* vsrc = &V[base + (size_t)(j0 + sj)*NE + sc];
      f16x8 vv0 = *(const f16x8*)vsrc;
      f16x8 vv1 = *(const f16x8*)(vsrc + 8);
      #pragma unroll
      for (int i = 0; i < 8; ++i) Vt[(sc + i)*72 + sj]     = vv0[i];
      #pragma unroll
      for (int i = 0; i < 8; ++i) Vt[(sc + 8 + i)*72 + sj] = vv1[i];
    }
    __syncthreads();

    // S = Q K^T  (raw, scaled by 1/8 in softmax)
    f32x4 s[2][4];
    #pragma unroll
    for (int rg = 0; rg < 2; ++rg)
      #pragma unroll
      for (int cf = 0; cf < 4; ++cf) s[rg][cf] = f32x4{0.f, 0.f, 0.f, 0.f};
    #pragma unroll
    for (int kf = 0; kf < 2; ++kf)
      #pragma unroll
      for (int cf = 0; cf < 4; ++cf) {
        f16x8 bk = *(const f16x8*)&Ks[(cf*16 + (l&15))*72 + kf*32 + ((l>>4)<<3)];
        #pragma unroll
        for (int rg = 0; rg < 2; ++rg)
          s[rg][cf] = __builtin_amdgcn_mfma_f32_16x16x32_f16(aq[rg][kf], bk, s[rg][cf], 0, 0, 0);
      }

    // online softmax (f32); C layout: col=l&15, row=(l>>4)*4+r
    #pragma unroll
    for (int rg = 0; rg < 2; ++rg)
      #pragma unroll
      for (int r = 0; r < 4; ++r) {
        float mx = fmaxf(fmaxf(s[rg][0][r], s[rg][1][r]), fmaxf(s[rg][2][r], s[rg][3][r])) * 0.125f;
        #pragma unroll
        for (int msk = 1; msk < 16; msk <<= 1) mx = fmaxf(mx, __shfl_xor(mx, msk));
        const float mnew  = fmaxf(mrow[rg][r], mx);
        const float alpha = __expf(mrow[rg][r] - mnew);
        mrow[rg][r] = mnew;
        float psum = 0.f;
        #pragma unroll
        for (int cf = 0; cf < 4; ++cf) {
          float p = __expf(s[rg][cf][r]*0.125f - mnew);
          s[rg][cf][r] = p;
          psum += p;
        }
        #pragma unroll
        for (int msk = 1; msk < 16; msk <<= 1) psum += __shfl_xor(psum, msk);
        lrow[rg][r] = lrow[rg][r]*alpha + psum;
        #pragma unroll
        for (int df = 0; df < 4; ++df) o[rg][df][r] *= alpha;
      }

    // P -> f16 in per-wave LDS (padded rows)
    #pragma unroll
    for (int rg = 0; rg < 2; ++rg)
      #pragma unroll
      for (int cf = 0; cf < 4; ++cf)
        #pragma unroll
        for (int r = 0; r < 4; ++r)
          Ps[w][(rg*16 + ((l>>4)<<2) + r)*72 + cf*16 + (l&15)] = (f16)s[rg][cf][r];
    __syncthreads();

    // O += P V
    #pragma unroll
    for (int kf2 = 0; kf2 < 2; ++kf2) {
      f16x8 pa[2];
      #pragma unroll
      for (int rg = 0; rg < 2; ++rg)
        pa[rg] = *(const f16x8*)&Ps[w][(rg*16 + (l&15))*72 + kf2*32 + ((l>>4)<<3)];
      #pragma unroll
      for (int df = 0; df < 4; ++df) {
        f16x8 bv = *(const f16x8*)&Vt[(df*16 + (l&15))*72 + kf2*32 + ((l>>4)<<3)];
        #pragma unroll
        for (int rg = 0; rg < 2; ++rg)
          o[rg][df] = __builtin_amdgcn_mfma_f32_16x16x32_f16(pa[rg], bv, o[rg][df], 0, 0, 0);
      }
    }
  }

  // epilogue: normalize, store f16 [B,S,E]
  #pragma unroll
  for (int rg = 0; rg < 2; ++rg)
    #pragma unroll
    for (int r = 0; r < 4; ++r) {
      const float inv = 1.0f / lrow[rg][r];
      const int row = q0 + rg*16 + ((l>>4)<<2) + r;
      #pragma unroll
      for (int df = 0; df < 4; ++df)
        O[base + (size_t)row*NE + df*16 + (l&15)] = (f16)(o[rg][df][r] * inv);
    }
}

// ---------------- launch ----------------
extern "C" void kernel_launch(void* const* d_in, const int* in_sizes, int n_in,
                              void* d_out, int out_size, void* d_ws, size_t ws_size,
                              hipStream_t stream)
{
  const float* q_in = (const float*)d_in[0];
  const float* k_in = (const float*)d_in[1];
  const float* v_in = (const float*)d_in[2];
  const float* Wq = (const float*)d_in[3];
  const float* bq = (const float*)d_in[4];
  const float* Wk = (const float*)d_in[5];
  const float* bk = (const float*)d_in[6];
  const float* Wv = (const float*)d_in[7];
  const float* bv = (const float*)d_in[8];
  const float* Wo = (const float*)d_in[9];
  const float* bo = (const float*)d_in[10];

  char* ws = (char*)d_ws;
  // f16 workspace layout (total 120 MB)
  f16* Xq   = (f16*)(ws + 0);           // 16 MB each
  f16* Xk   = (f16*)(ws + 16777216);
  f16* Xv   = (f16*)(ws + 33554432);
  f16* Wq16 = (f16*)(ws + 50331648);    // 2 MB each
  f16* Wk16 = (f16*)(ws + 52428800);
  f16* Wv16 = (f16*)(ws + 54525952);
  f16* Wo16 = (f16*)(ws + 56623104);
  f16* Qp   = (f16*)(ws + 58720256);
  f16* Kp   = (f16*)(ws + 75497472);
  f16* Vp   = (f16*)(ws + 92274688);
  f16* Op   = (f16*)(ws + 109051904);

  cvt_kernel<<<1024, 256, 0, stream>>>(q_in, Xq, NM*NE/4);
  cvt_kernel<<<1024, 256, 0, stream>>>(k_in, Xk, NM*NE/4);
  cvt_kernel<<<1024, 256, 0, stream>>>(v_in, Xv, NM*NE/4);
  cvt_kernel<<<1024, 256, 0, stream>>>(Wq, Wq16, NE*NE/4);
  cvt_kernel<<<1024, 256, 0, stream>>>(Wk, Wk16, NE*NE/4);
  cvt_kernel<<<1024, 256, 0, stream>>>(Wv, Wv16, NE*NE/4);
  cvt_kernel<<<1024, 256, 0, stream>>>(Wo, Wo16, NE*NE/4);

  dim3 gg(8, 64);  // (N/128, M/128)
  gemm_bt<false><<<gg, 256, 0, stream>>>(Xq, Wq16, bq, nullptr, Qp, NM, NE, NE);
  gemm_bt<false><<<gg, 256, 0, stream>>>(Xk, Wk16, bk, nullptr, Kp, NM, NE, NE);
  gemm_bt<false><<<gg, 256, 0, stream>>>(Xv, Wv16, bv, nullptr, Vp, NM, NE, NE);

  attn_kernel<<<dim3(16, 64), 256, 0, stream>>>(Qp, Kp, Vp, Op);

  gemm_bt<true><<<gg, 256, 0, stream>>>(Op, Wo16, bo, (float*)d_out, nullptr, NM, NE, NE);
}

// Round 3
// 298.330 us; speedup vs baseline: 1.5084x; 1.5084x over previous
//
#include <hip/hip_runtime.h>

typedef _Float16 f16;
typedef __attribute__((ext_vector_type(2))) __fp16 fp16x2_raw;
typedef __attribute__((ext_vector_type(4))) _Float16 f16x4;
typedef __attribute__((ext_vector_type(8))) _Float16 f16x8;
typedef __attribute__((ext_vector_type(4))) float f32x4;
typedef __attribute__((ext_vector_type(16))) float f32x16;
typedef __attribute__((ext_vector_type(2))) unsigned int u32x2;

#define NB 4
#define NS 2048
#define NE 1024
#define NH 16
#define ND 64
#define NM (NB*NS)   // 8192 tokens

__device__ __forceinline__ void gld16(const void* g, void* l) {
  __builtin_amdgcn_global_load_lds((const __attribute__((address_space(1))) unsigned int*)g,
                                   (__attribute__((address_space(3))) unsigned int*)l, 16, 0, 0);
}

// pack two f32 -> one u32 of 2 f16 (v_cvt_pkrtz_f16_f32)
__device__ __forceinline__ unsigned cvt2h(float a, float b) {
  fp16x2_raw r = __builtin_amdgcn_cvt_pkrtz(a, b);
  return __builtin_bit_cast(unsigned, r);
}

// ---------------- fused f32 -> f16 convert (7 tensors, contiguous dest in ws) ----------------
__global__ __launch_bounds__(256) void cvt_all(const float* __restrict__ s0, const float* __restrict__ s1,
                                               const float* __restrict__ s2, const float* __restrict__ s3,
                                               const float* __restrict__ s4, const float* __restrict__ s5,
                                               const float* __restrict__ s6, f16* __restrict__ dst) {
  const int X = NM*NE/4;      // 2097152 float4s per activation
  const int W = NE*NE/4;      // 262144 per weight
  const int total = 3*X + 4*W;
  int idx = blockIdx.x * blockDim.x + threadIdx.x;
  int stride = gridDim.x * blockDim.x;
  for (int i = idx; i < total; i += stride) {
    const float* src; int off;
    if      (i <   X)     { src = s0; off = i; }
    else if (i < 2*X)     { src = s1; off = i - X; }
    else if (i < 3*X)     { src = s2; off = i - 2*X; }
    else if (i < 3*X+W)   { src = s3; off = i - 3*X; }
    else if (i < 3*X+2*W) { src = s4; off = i - (3*X+W); }
    else if (i < 3*X+3*W) { src = s5; off = i - (3*X+2*W); }
    else                  { src = s6; off = i - (3*X+3*W); }
    float4 v = ((const float4*)src)[off];
    f16x4 o;
    o[0] = (_Float16)v.x; o[1] = (_Float16)v.y; o[2] = (_Float16)v.z; o[3] = (_Float16)v.w;
    ((f16x4*)dst)[i] = o;
  }
}

// ---------------- NT GEMM: C = A[M,K] * B[N,K]^T + bias (m97 structure) ----------------
template<bool OUTF32>
__global__ __launch_bounds__(256)
void gemm_bt(const f16* __restrict__ A, const f16* __restrict__ Bw,
             const float* __restrict__ bias, float* __restrict__ Cf,
             f16* __restrict__ Ch, int M, int N, int K)
{
  __shared__ __align__(16) f16 As[128*32];
  __shared__ __align__(16) f16 Bs[128*32];
  const int t = threadIdx.x;
  const int l = t & 63, w = t >> 6;
  const int wr = w >> 1, wc = w & 1;
  const int m0 = blockIdx.y * 128, n0 = blockIdx.x * 128;

  f32x4 acc[4][4];
  #pragma unroll
  for (int i = 0; i < 4; ++i)
    #pragma unroll
    for (int j = 0; j < 4; ++j)
      acc[i][j] = f32x4{0.f, 0.f, 0.f, 0.f};

  const int off0 = (w*2+0)*1024 + l*16;
  const int off1 = (w*2+1)*1024 + l*16;
  const int row0 = off0 >> 6, k0 = (off0 & 63) >> 1;
  const int row1 = off1 >> 6, k1 = (off1 & 63) >> 1;
  const f16* a0 = A  + (size_t)(m0+row0)*K + k0;
  const f16* a1 = A  + (size_t)(m0+row1)*K + k1;
  const f16* b0 = Bw + (size_t)(n0+row0)*K + k0;
  const f16* b1 = Bw + (size_t)(n0+row1)*K + k1;
  f16* As0 = As + off0/2; f16* As1 = As + off1/2;
  f16* Bs0 = Bs + off0/2; f16* Bs1 = Bs + off1/2;

  const int aoff = (wr*64 + (l&15))*32 + ((l>>4)<<3);
  const int boff = (wc*64 + (l&15))*32 + ((l>>4)<<3);

  for (int kt = 0; kt < K; kt += 32) {
    __syncthreads();
    gld16(a0 + kt, As0);
    gld16(a1 + kt, As1);
    gld16(b0 + kt, Bs0);
    gld16(b1 + kt, Bs1);
    __syncthreads();
    f16x8 af[4], bf[4];
    #pragma unroll
    for (int i = 0; i < 4; ++i) af[i] = *(const f16x8*)(As + aoff + i*512);
    #pragma unroll
    for (int j = 0; j < 4; ++j) bf[j] = *(const f16x8*)(Bs + boff + j*512);
    #pragma unroll
    for (int i = 0; i < 4; ++i)
      #pragma unroll
      for (int j = 0; j < 4; ++j)
        acc[i][j] = __builtin_amdgcn_mfma_f32_16x16x32_f16(af[i], bf[j], acc[i][j], 0, 0, 0);
  }

  #pragma unroll
  for (int j = 0; j < 4; ++j) {
    const int col = n0 + wc*64 + j*16 + (l & 15);
    const float bb = bias[col];
    #pragma unroll
    for (int i = 0; i < 4; ++i) {
      const int rowb = m0 + wr*64 + i*16 + ((l>>4)<<2);
      #pragma unroll
      for (int r = 0; r < 4; ++r) {
        float v = acc[i][j][r] + bb;
        if constexpr (OUTF32) Cf[(size_t)(rowb+r)*N + col] = v;
        else                  Ch[(size_t)(rowb+r)*N + col] = (f16)v;
      }
    }
  }
}

// ---------------- flash attention, swapped-operand 32x32 MFMA ----------------
// grid 1024 blocks (XCD-swizzled), 256 thr = 4 waves, wave owns 32 q rows.
// S^T = mfma(K, Q): lane holds 32 scores for q = lane&31 -> in-lane softmax.
// O^T = mfma(V^T, P): lane accumulates O[q=lane&31][16 d per tile] -> local rescale.
// P stays in registers: cvt_pkrtz pack + shfl_xor(32) exchange builds PV B-frag.
__global__ __launch_bounds__(256)
void attn_kernel(const f16* __restrict__ Q, const f16* __restrict__ K,
                 const f16* __restrict__ V, f16* __restrict__ O)
{
  __shared__ __align__(16) f16 Ks[64*64];   // [key][d] XOR-swizzled
  __shared__ __align__(16) f16 Vt[64*64];   // [d][key] XOR-swizzled

  const int t = threadIdx.x, l = t & 63, w = t >> 6;
  const int lq = l & 31, hi = l >> 5;

  // XCD-bijective swizzle: all 16 q-tiles of one bh land on one XCD (L2 reuse of K/V)
  const int lin = blockIdx.x + (blockIdx.y << 4);
  const int xcd = lin & 7, j = lin >> 3;
  const int bh = xcd * 8 + (j >> 4);
  const int qt = j & 15;
  const int b = bh >> 4, h = bh & 15;
  const size_t base = (size_t)b * NS * NE + (size_t)h * ND;
  const int q = qt*128 + w*32 + lq;

  // Q B-fragments (held in regs): bq[ks][j8] = Q[q][ks*16 + hi*8 + j8]
  f16x8 bq[4];
  #pragma unroll
  for (int ks = 0; ks < 4; ++ks)
    bq[ks] = *(const f16x8*)&Q[base + (size_t)q*NE + ks*16 + hi*8];

  f32x16 o[2];
  #pragma unroll
  for (int dt = 0; dt < 2; ++dt)
    #pragma unroll
    for (int r = 0; r < 16; ++r) o[dt][r] = 0.f;
  float m2 = -3e38f, lsum = 0.f;
  const float K2 = 0.125f * 1.44269504089f;   // scale * log2(e)

  // staging: thread t loads row sj, d-chunk sc4*16..+15 (K and V)
  const int sj = t >> 2, sc4 = t & 3;
  const f16* kptr = &K[base + (size_t)sj*NE + sc4*16];
  const f16* vptr = &V[base + (size_t)sj*NE + sc4*16];
  char* ksb = (char*)Ks;
  char* vtb = (char*)Vt;
  const int kaddrA = sj*128 + sc4*32;
  const int kswz = (sj & 7) << 4;

  for (int j0 = 0; j0 < NS; j0 += 64) {
    __syncthreads();
    // ---- stage K (vectorized, swizzled) and V (transposed scalar) ----
    f16x8 kv0 = *(const f16x8*)(kptr + (size_t)j0*NE);
    f16x8 kv1 = *(const f16x8*)(kptr + (size_t)j0*NE + 8);
    f16x8 vv0 = *(const f16x8*)(vptr + (size_t)j0*NE);
    f16x8 vv1 = *(const f16x8*)(vptr + (size_t)j0*NE + 8);
    *(f16x8*)(ksb + (kaddrA ^ kswz))        = kv0;
    *(f16x8*)(ksb + ((kaddrA + 16) ^ kswz)) = kv1;
    #pragma unroll
    for (int i = 0; i < 8; ++i) {
      const int d0 = sc4*16 + i, d1 = sc4*16 + 8 + i;
      *(f16*)(vtb + ((d0*128 + sj*2) ^ ((d0 & 7) << 4))) = vv0[i];
      *(f16*)(vtb + ((d1*128 + sj*2) ^ ((d1 & 7) << 4))) = vv1[i];
    }
    __syncthreads();

    // ---- S^T = K * Q^T : s[ct] holds keys ct*32 + crow(r,hi), q = lq ----
    f32x16 s[2];
    #pragma unroll
    for (int ct = 0; ct < 2; ++ct)
      #pragma unroll
      for (int r = 0; r < 16; ++r) s[ct][r] = 0.f;
    #pragma unroll
    for (int ct = 0; ct < 2; ++ct) {
      const int krow = ct*32 + lq;
      const int rswz = (krow & 7) << 4;
      #pragma unroll
      for (int ks = 0; ks < 4; ++ks) {
        f16x8 ak = *(const f16x8*)(ksb + ((krow*128 + (ks*16 + hi*8)*2) ^ rswz));
        s[ct] = __builtin_amdgcn_mfma_f32_32x32x16_f16(ak, bq[ks], s[ct], 0, 0, 0);
      }
    }

    // ---- in-lane online softmax (base-2 domain), q = lq ----
    float mx = s[0][0];
    #pragma unroll
    for (int ct = 0; ct < 2; ++ct)
      #pragma unroll
      for (int r = 0; r < 16; ++r) mx = fmaxf(mx, s[ct][r]);
    mx *= K2;
    mx = fmaxf(mx, __shfl_xor(mx, 32));
    const float mnew = fmaxf(m2, mx);
    const float alpha = __builtin_amdgcn_exp2f(m2 - mnew);
    m2 = mnew;
    float psum = 0.f;
    #pragma unroll
    for (int ct = 0; ct < 2; ++ct)
      #pragma unroll
      for (int r = 0; r < 16; ++r) {
        float p = __builtin_amdgcn_exp2f(s[ct][r]*K2 - mnew);
        s[ct][r] = p;
        psum += p;
      }
    psum += __shfl_xor(psum, 32);
    lsum = lsum*alpha + psum;
    #pragma unroll
    for (int dt = 0; dt < 2; ++dt)
      #pragma unroll
      for (int r = 0; r < 16; ++r) o[dt][r] *= alpha;

    // ---- P -> f16 words, cross-hi exchange, PV MFMA ----
    #pragma unroll
    for (int ct = 0; ct < 2; ++ct) {
      unsigned wd[8];
      #pragma unroll
      for (int m = 0; m < 4; ++m)
        #pragma unroll
        for (int hh = 0; hh < 2; ++hh)
          wd[m*2 + hh] = cvt2h(s[ct][4*m + 2*hh], s[ct][4*m + 2*hh + 1]);
      #pragma unroll
      for (int ks2 = 0; ks2 < 2; ++ks2) {
        const unsigned w0h0 = wd[(2*ks2)*2 + 0],   w0h1 = wd[(2*ks2)*2 + 1];
        const unsigned w1h0 = wd[(2*ks2+1)*2 + 0], w1h1 = wd[(2*ks2+1)*2 + 1];
        const unsigned p0h0 = __shfl_xor(w0h0, 32), p0h1 = __shfl_xor(w0h1, 32);
        const unsigned p1h0 = __shfl_xor(w1h0, 32), p1h1 = __shfl_xor(w1h1, 32);
        union { unsigned u[4]; f16x8 v; } pa;
        pa.u[0] = (hi == 0) ? w0h0 : p1h0;   // keys +8hi+{0,1}
        pa.u[1] = (hi == 0) ? w0h1 : p1h1;   // keys +8hi+{2,3}
        pa.u[2] = (hi == 0) ? p0h0 : w1h0;   // keys +8hi+{4,5}
        pa.u[3] = (hi == 0) ? p0h1 : w1h1;   // keys +8hi+{6,7}
        const int ks = ct*2 + ks2;           // global 16-key slice
        #pragma unroll
        for (int dt = 0; dt < 2; ++dt) {
          const int drow = dt*32 + lq;
          f16x8 av = *(const f16x8*)(vtb + ((drow*128 + (ks*16 + hi*8)*2) ^ ((drow & 7) << 4)));
          o[dt] = __builtin_amdgcn_mfma_f32_32x32x16_f16(av, pa.v, o[dt], 0, 0, 0);
        }
      }
    }
  }

  // ---- epilogue: lane holds O[q=lq][d = dt*32 + 8*m + 4*hi + (0..3)], normalize, store ----
  const float linv = 1.0f / lsum;
  #pragma unroll
  for (int dt = 0; dt < 2; ++dt)
    #pragma unroll
    for (int m = 0; m < 4; ++m) {
      u32x2 st;
      st.x = cvt2h(o[dt][4*m+0]*linv, o[dt][4*m+1]*linv);
      st.y = cvt2h(o[dt][4*m+2]*linv, o[dt][4*m+3]*linv);
      const int d = dt*32 + 8*m + 4*hi;
      *(u32x2*)&O[base + (size_t)q*NE + d] = st;
    }
}

// ---------------- launch ----------------
extern "C" void kernel_launch(void* const* d_in, const int* in_sizes, int n_in,
                              void* d_out, int out_size, void* d_ws, size_t ws_size,
                              hipStream_t stream)
{
  const float* q_in = (const float*)d_in[0];
  const float* k_in = (const float*)d_in[1];
  const float* v_in = (const float*)d_in[2];
  const float* Wq = (const float*)d_in[3];
  const float* bq = (const float*)d_in[4];
  const float* Wk = (const float*)d_in[5];
  const float* bk = (const float*)d_in[6];
  const float* Wv = (const float*)d_in[7];
  const float* bv = (const float*)d_in[8];
  const float* Wo = (const float*)d_in[9];
  const float* bo = (const float*)d_in[10];

  char* ws = (char*)d_ws;
  f16* Xq   = (f16*)(ws + 0);
  f16* Xk   = (f16*)(ws + 16777216);
  f16* Xv   = (f16*)(ws + 33554432);
  f16* Wq16 = (f16*)(ws + 50331648);
  f16* Wk16 = (f16*)(ws + 52428800);
  f16* Wv16 = (f16*)(ws + 54525952);
  f16* Wo16 = (f16*)(ws + 56623104);
  f16* Qp   = (f16*)(ws + 58720256);
  f16* Kp   = (f16*)(ws + 75497472);
  f16* Vp   = (f16*)(ws + 92274688);
  f16* Op   = (f16*)(ws + 109051904);

  cvt_all<<<2048, 256, 0, stream>>>(q_in, k_in, v_in, Wq, Wk, Wv, Wo, Xq);

  dim3 gg(8, 64);  // (N/128, M/128)
  gemm_bt<false><<<gg, 256, 0, stream>>>(Xq, Wq16, bq, nullptr, Qp, NM, NE, NE);
  gemm_bt<false><<<gg, 256, 0, stream>>>(Xk, Wk16, bk, nullptr, Kp, NM, NE, NE);
  gemm_bt<false><<<gg, 256, 0, stream>>>(Xv, Wv16, bv, nullptr, Vp, NM, NE, NE);

  attn_kernel<<<dim3(16, 64), 256, 0, stream>>>(Qp, Kp, Vp, Op);

  gemm_bt<true><<<gg, 256, 0, stream>>>(Op, Wo16, bo, (float*)d_out, nullptr, NM, NE, NE);
}

// Round 8
// 275.465 us; speedup vs baseline: 1.6336x; 1.0830x over previous
//
#include <hip/hip_runtime.h>

typedef _Float16 f16;
typedef __attribute__((ext_vector_type(2))) __fp16 fp16x2_raw;
typedef __attribute__((ext_vector_type(4))) _Float16 f16x4;
typedef __attribute__((ext_vector_type(8))) _Float16 f16x8;
typedef __attribute__((ext_vector_type(4))) float f32x4;
typedef __attribute__((ext_vector_type(16))) float f32x16;
typedef __attribute__((ext_vector_type(2))) unsigned int u32x2;

#define NB 4
#define NS 2048
#define NE 1024
#define NH 16
#define ND 64
#define NM (NB*NS)   // 8192 tokens

__device__ __forceinline__ void gld16(const void* g, void* l) {
  __builtin_amdgcn_global_load_lds((const __attribute__((address_space(1))) unsigned int*)g,
                                   (__attribute__((address_space(3))) unsigned int*)l, 16, 0, 0);
}

// pack two f32 -> one u32 of 2 f16 (v_cvt_pkrtz_f16_f32)
__device__ __forceinline__ unsigned cvt2h(float a, float b) {
  fp16x2_raw r = __builtin_amdgcn_cvt_pkrtz(a, b);
  return __builtin_bit_cast(unsigned, r);
}

// ---------------- fused f32 -> f16 convert ----------------
__global__ __launch_bounds__(256) void cvt_all(const float* __restrict__ s0, const float* __restrict__ s1,
                                               const float* __restrict__ s2, const float* __restrict__ s3,
                                               const float* __restrict__ s4, const float* __restrict__ s5,
                                               const float* __restrict__ s6, f16* __restrict__ dst) {
  const int X = NM*NE/4;
  const int W = NE*NE/4;
  const int total = 3*X + 4*W;
  int idx = blockIdx.x * blockDim.x + threadIdx.x;
  int stride = gridDim.x * blockDim.x;
  for (int i = idx; i < total; i += stride) {
    const float* src; int off;
    if      (i <   X)     { src = s0; off = i; }
    else if (i < 2*X)     { src = s1; off = i - X; }
    else if (i < 3*X)     { src = s2; off = i - 2*X; }
    else if (i < 3*X+W)   { src = s3; off = i - 3*X; }
    else if (i < 3*X+2*W) { src = s4; off = i - (3*X+W); }
    else if (i < 3*X+3*W) { src = s5; off = i - (3*X+2*W); }
    else                  { src = s6; off = i - (3*X+3*W); }
    float4 v = ((const float4*)src)[off];
    f16x4 o;
    o[0] = (_Float16)v.x; o[1] = (_Float16)v.y; o[2] = (_Float16)v.z; o[3] = (_Float16)v.w;
    ((f16x4*)dst)[i] = o;
  }
}

// ---------------- NT GEMM: C = A[M,K] * B[N,K]^T + bias (m97 structure) ----------------
template<bool OUTF32>
__global__ __launch_bounds__(256)
void gemm_bt(const f16* __restrict__ A, const f16* __restrict__ Bw,
             const float* __restrict__ bias, float* __restrict__ Cf,
             f16* __restrict__ Ch, int M, int N, int K)
{
  __shared__ __align__(16) f16 As[128*32];
  __shared__ __align__(16) f16 Bs[128*32];
  const int t = threadIdx.x;
  const int l = t & 63, w = t >> 6;
  const int wr = w >> 1, wc = w & 1;
  const int m0 = blockIdx.y * 128, n0 = blockIdx.x * 128;

  f32x4 acc[4][4];
  #pragma unroll
  for (int i = 0; i < 4; ++i)
    #pragma unroll
    for (int j = 0; j < 4; ++j)
      acc[i][j] = f32x4{0.f, 0.f, 0.f, 0.f};

  const int off0 = (w*2+0)*1024 + l*16;
  const int off1 = (w*2+1)*1024 + l*16;
  const int row0 = off0 >> 6, k0 = (off0 & 63) >> 1;
  const int row1 = off1 >> 6, k1 = (off1 & 63) >> 1;
  const f16* a0 = A  + (size_t)(m0+row0)*K + k0;
  const f16* a1 = A  + (size_t)(m0+row1)*K + k1;
  const f16* b0 = Bw + (size_t)(n0+row0)*K + k0;
  const f16* b1 = Bw + (size_t)(n0+row1)*K + k1;
  f16* As0 = As + off0/2; f16* As1 = As + off1/2;
  f16* Bs0 = Bs + off0/2; f16* Bs1 = Bs + off1/2;

  const int aoff = (wr*64 + (l&15))*32 + ((l>>4)<<3);
  const int boff = (wc*64 + (l&15))*32 + ((l>>4)<<3);

  for (int kt = 0; kt < K; kt += 32) {
    __syncthreads();
    gld16(a0 + kt, As0);
    gld16(a1 + kt, As1);
    gld16(b0 + kt, Bs0);
    gld16(b1 + kt, Bs1);
    __syncthreads();
    f16x8 af[4], bf[4];
    #pragma unroll
    for (int i = 0; i < 4; ++i) af[i] = *(const f16x8*)(As + aoff + i*512);
    #pragma unroll
    for (int j = 0; j < 4; ++j) bf[j] = *(const f16x8*)(Bs + boff + j*512);
    #pragma unroll
    for (int i = 0; i < 4; ++i)
      #pragma unroll
      for (int j = 0; j < 4; ++j)
        acc[i][j] = __builtin_amdgcn_mfma_f32_16x16x32_f16(af[i], bf[j], acc[i][j], 0, 0, 0);
  }

  #pragma unroll
  for (int j = 0; j < 4; ++j) {
    const int col = n0 + wc*64 + j*16 + (l & 15);
    const float bb = bias[col];
    #pragma unroll
    for (int i = 0; i < 4; ++i) {
      const int rowb = m0 + wr*64 + i*16 + ((l>>4)<<2);
      #pragma unroll
      for (int r = 0; r < 4; ++r) {
        float v = acc[i][j][r] + bb;
        if constexpr (OUTF32) Cf[(size_t)(rowb+r)*N + col] = v;
        else                  Ch[(size_t)(rowb+r)*N + col] = (f16)v;
      }
    }
  }
}

// ---------------- flash attention: swapped 32x32 MFMA ----------------
// K: [64 key][64 d] XOR-swizzled, staged via global_load_lds with inverse-permuted source (audited == R3 image).
// V: R3-PROVEN path — register load + transposed scalar ds_write_b16 into XOR-swizzled Vt[d][key];
//    PV A-frag read as straight f16x8 (tr_read empirically convicted, removed).
// P: in-register (cvt_pkrtz + shfl_xor(32) + select), no LDS round-trip.
__global__ __launch_bounds__(256, 4)
void attn_kernel(const f16* __restrict__ Q, const f16* __restrict__ K,
                 const f16* __restrict__ V, f16* __restrict__ O)
{
  __shared__ __align__(16) f16 S_lds[8192];   // [0,4096): K tile (8KB), [4096,8192): Vt tile (8KB)

  const int t = threadIdx.x, l = t & 63, w = t >> 6;
  const int lq = l & 31, hi = l >> 5;

  // XCD-bijective swizzle: all 16 q-tiles of one bh on one XCD
  const int lin = blockIdx.x + (blockIdx.y << 4);
  const int xcd = lin & 7, jj = lin >> 3;
  const int bh = xcd * 8 + (jj >> 4);
  const int qt = jj & 15;
  const int b = bh >> 4, h = bh & 15;
  const size_t base = (size_t)b * NS * NE + (size_t)h * ND;
  const int q = qt*128 + w*32 + lq;

  // Q B-fragments
  f16x8 bq[4];
  #pragma unroll
  for (int ks = 0; ks < 4; ++ks)
    bq[ks] = *(const f16x8*)&Q[base + (size_t)q*NE + ks*16 + hi*8];
  asm volatile("s_waitcnt vmcnt(0)" ::: "memory");

  f32x16 o[2];
  #pragma unroll
  for (int dt = 0; dt < 2; ++dt)
    #pragma unroll
    for (int r = 0; r < 16; ++r) o[dt][r] = 0.f;
  float m2 = -3e38f, lsum = 0.f;
  const float K2 = 0.125f * 1.44269504089f;

  // ---- K staging via gld_lds (inverse-permuted source; image == R3's) ----
  const int krow0 = w*16 + (l>>3);
  const int kgran = ((l&7) ^ (l>>3)) * 8;
  const f16* kSrc0 = K + base + (size_t)krow0*NE + kgran;
  const f16* kSrc1 = kSrc0 + (size_t)8*NE;
  f16* kDst0 = &S_lds[0] + (w*2+0)*512 + l*8;
  f16* kDst1 = &S_lds[0] + (w*2+1)*512 + l*8;

  // ---- V staging (R3-proven): thread loads key sj, d-chunk sc4*16..+15; scalar transpose writes ----
  const int sj = t >> 2, sc4 = t & 3;
  const f16* vptr = &V[base + (size_t)sj*NE + sc4*16];
  const char* ksb = (const char*)&S_lds[0];
  char* vtb = (char*)&S_lds[4096];

  const size_t tileAdv = (size_t)64 * NE;

  for (int it = 0; it < 32; ++it) {
    const size_t g = (size_t)it * tileAdv;
    __syncthreads();
    gld16(kSrc0 + g, kDst0);
    gld16(kSrc1 + g, kDst1);
    {
      f16x8 vv0 = *(const f16x8*)(vptr + g);
      f16x8 vv1 = *(const f16x8*)(vptr + g + 8);
      #pragma unroll
      for (int i = 0; i < 8; ++i) {
        const int d0 = sc4*16 + i, d1 = sc4*16 + 8 + i;
        *(f16*)(vtb + ((d0*128 + sj*2) ^ ((d0 & 7) << 4))) = vv0[i];
        *(f16*)(vtb + ((d1*128 + sj*2) ^ ((d1 & 7) << 4))) = vv1[i];
      }
    }
    __syncthreads();   // drains vmcnt(0) (K DMA) + lgkmcnt (V writes)

    // ---- S^T = K * Q^T ----
    f32x16 s[2];
    #pragma unroll
    for (int ct = 0; ct < 2; ++ct)
      #pragma unroll
      for (int r = 0; r < 16; ++r) s[ct][r] = 0.f;
    #pragma unroll
    for (int ct = 0; ct < 2; ++ct) {
      const int krow = ct*32 + lq;
      const int rswz = (krow & 7) << 4;
      #pragma unroll
      for (int ks = 0; ks < 4; ++ks) {
        f16x8 ak = *(const f16x8*)(ksb + ((krow*128 + ks*32 + hi*16) ^ rswz));
        s[ct] = __builtin_amdgcn_mfma_f32_32x32x16_f16(ak, bq[ks], s[ct], 0, 0, 0);
      }
    }

    // ---- in-lane online softmax (base-2) ----
    float mx = fmaxf(s[0][0], s[1][0]);
    #pragma unroll
    for (int r = 1; r < 16; ++r) mx = fmaxf(mx, fmaxf(s[0][r], s[1][r]));
    mx *= K2;
    mx = fmaxf(mx, __shfl_xor(mx, 32));
    const float mnew = fmaxf(m2, mx);
    const float alpha = __builtin_amdgcn_exp2f(m2 - mnew);
    m2 = mnew;
    float ps = 0.f;
    #pragma unroll
    for (int ct = 0; ct < 2; ++ct)
      #pragma unroll
      for (int r = 0; r < 16; ++r) {
        float p = __builtin_amdgcn_exp2f(s[ct][r]*K2 - mnew);
        s[ct][r] = p;
        ps += p;
      }
    lsum = lsum*alpha + ps;     // per-lane partial; cross-half combine at end
    #pragma unroll
    for (int dt = 0; dt < 2; ++dt)
      #pragma unroll
      for (int r = 0; r < 16; ++r) o[dt][r] *= alpha;

    // ---- pack P, build PV B-operands (R3-proven shfl_xor + select) ----
    f16x8 pa[4];
    #pragma unroll
    for (int ct = 0; ct < 2; ++ct) {
      unsigned wd[8];
      #pragma unroll
      for (int m = 0; m < 4; ++m)
        #pragma unroll
        for (int hh = 0; hh < 2; ++hh)
          wd[m*2 + hh] = cvt2h(s[ct][4*m + 2*hh], s[ct][4*m + 2*hh + 1]);
      #pragma unroll
      for (int ks2 = 0; ks2 < 2; ++ks2) {
        const unsigned w0h0 = wd[(2*ks2)*2 + 0],   w0h1 = wd[(2*ks2)*2 + 1];
        const unsigned w1h0 = wd[(2*ks2+1)*2 + 0], w1h1 = wd[(2*ks2+1)*2 + 1];
        const unsigned p0h0 = __shfl_xor(w0h0, 32), p0h1 = __shfl_xor(w0h1, 32);
        const unsigned p1h0 = __shfl_xor(w1h0, 32), p1h1 = __shfl_xor(w1h1, 32);
        union { unsigned u[4]; f16x8 v; } pp;
        pp.u[0] = (hi == 0) ? w0h0 : p1h0;   // keys +8hi+{0,1}
        pp.u[1] = (hi == 0) ? w0h1 : p1h1;   // keys +8hi+{2,3}
        pp.u[2] = (hi == 0) ? p0h0 : w1h0;   // keys +8hi+{4,5}
        pp.u[3] = (hi == 0) ? p0h1 : w1h1;   // keys +8hi+{6,7}
        pa[ct*2 + ks2] = pp.v;
      }
    }

    // ---- O^T += V^T * P : A-frags straight f16x8 from swizzled Vt (R3-proven) ----
    #pragma unroll
    for (int ks = 0; ks < 4; ++ks)
      #pragma unroll
      for (int dt = 0; dt < 2; ++dt) {
        const int drow = dt*32 + lq;
        f16x8 av = *(const f16x8*)(vtb + ((drow*128 + ks*32 + hi*16) ^ ((drow & 7) << 4)));
        o[dt] = __builtin_amdgcn_mfma_f32_32x32x16_f16(av, pa[ks], o[dt], 0, 0, 0);
      }
  }

  // ---- epilogue: cross-half lsum combine, normalize, store ----
  float lt = lsum + __shfl_xor(lsum, 32);
  const float linv = 1.0f / lt;
  #pragma unroll
  for (int dt = 0; dt < 2; ++dt)
    #pragma unroll
    for (int m = 0; m < 4; ++m) {
      u32x2 st;
      st.x = cvt2h(o[dt][4*m+0]*linv, o[dt][4*m+1]*linv);
      st.y = cvt2h(o[dt][4*m+2]*linv, o[dt][4*m+3]*linv);
      const int d = dt*32 + 8*m + 4*hi;
      *(u32x2*)&O[base + (size_t)q*NE + d] = st;
    }
}

// ---------------- launch ----------------
extern "C" void kernel_launch(void* const* d_in, const int* in_sizes, int n_in,
                              void* d_out, int out_size, void* d_ws, size_t ws_size,
                              hipStream_t stream)
{
  const float* q_in = (const float*)d_in[0];
  const float* k_in = (const float*)d_in[1];
  const float* v_in = (const float*)d_in[2];
  const float* Wq = (const float*)d_in[3];
  const float* bq = (const float*)d_in[4];
  const float* Wk = (const float*)d_in[5];
  const float* bk = (const float*)d_in[6];
  const float* Wv = (const float*)d_in[7];
  const float* bv = (const float*)d_in[8];
  const float* Wo = (const float*)d_in[9];
  const float* bo = (const float*)d_in[10];

  char* ws = (char*)d_ws;
  f16* Xq   = (f16*)(ws + 0);
  f16* Xk   = (f16*)(ws + 16777216);
  f16* Xv   = (f16*)(ws + 33554432);
  f16* Wq16 = (f16*)(ws + 50331648);
  f16* Wk16 = (f16*)(ws + 52428800);
  f16* Wv16 = (f16*)(ws + 54525952);
  f16* Wo16 = (f16*)(ws + 56623104);
  f16* Qp   = (f16*)(ws + 58720256);
  f16* Kp   = (f16*)(ws + 75497472);
  f16* Vp   = (f16*)(ws + 92274688);
  f16* Op   = (f16*)(ws + 109051904);

  cvt_all<<<2048, 256, 0, stream>>>(q_in, k_in, v_in, Wq, Wk, Wv, Wo, Xq);

  dim3 gg(8, 64);
  gemm_bt<false><<<gg, 256, 0, stream>>>(Xq, Wq16, bq, nullptr, Qp, NM, NE, NE);
  gemm_bt<false><<<gg, 256, 0, stream>>>(Xk, Wk16, bk, nullptr, Kp, NM, NE, NE);
  gemm_bt<false><<<gg, 256, 0, stream>>>(Xv, Wv16, bv, nullptr, Vp, NM, NE, NE);

  attn_kernel<<<dim3(16, 64), 256, 0, stream>>>(Qp, Kp, Vp, Op);

  gemm_bt<true><<<gg, 256, 0, stream>>>(Op, Wo16, bo, (float*)d_out, nullptr, NM, NE, NE);
}

// Round 11
// 266.103 us; speedup vs baseline: 1.6911x; 1.0352x over previous
//
#include <hip/hip_runtime.h>

typedef _Float16 f16;
typedef __attribute__((ext_vector_type(2))) __fp16 fp16x2_raw;
typedef __attribute__((ext_vector_type(4))) _Float16 f16x4;
typedef __attribute__((ext_vector_type(8))) _Float16 f16x8;
typedef __attribute__((ext_vector_type(4))) float f32x4;
typedef __attribute__((ext_vector_type(16))) float f32x16;
typedef __attribute__((ext_vector_type(2))) unsigned int u32x2;

#define NB 4
#define NS 2048
#define NE 1024
#define NH 16
#define ND 64
#define NM (NB*NS)   // 8192 tokens

__device__ __forceinline__ void gld16(const void* g, void* l) {
  __builtin_amdgcn_global_load_lds((const __attribute__((address_space(1))) unsigned int*)g,
                                   (__attribute__((address_space(3))) unsigned int*)l, 16, 0, 0);
}

// pack two f32 -> one u32 of 2 f16 (v_cvt_pkrtz_f16_f32)
__device__ __forceinline__ unsigned cvt2h(float a, float b) {
  fp16x2_raw r = __builtin_amdgcn_cvt_pkrtz(a, b);
  return __builtin_bit_cast(unsigned, r);
}

// proven (R5==R6, distinct-value operands so no reg-coalesce hazard):
// new_a[l] = l<32 ? a[l] : b[l-32]; new_b[l] = l<32 ? a[l+32] : b[l]
__device__ __forceinline__ void plswap(unsigned& a, unsigned& b) {
  asm volatile("v_permlane32_swap_b32 %0, %1" : "+v"(a), "+v"(b));
}
// NOTE: an a==b plswap variant was miscompiled (R9/R10 failures — allocator may
// coalesce equal-valued operands into one VGPR). Cross-half reductions use
// proven __shfl_xor(x,32) instead.

// ---------------- fused f32 -> f16 convert ----------------
__global__ __launch_bounds__(256) void cvt_all(const float* __restrict__ s0, const float* __restrict__ s1,
                                               const float* __restrict__ s2, const float* __restrict__ s3,
                                               const float* __restrict__ s4, const float* __restrict__ s5,
                                               const float* __restrict__ s6, f16* __restrict__ dst) {
  const int X = NM*NE/4;
  const int W = NE*NE/4;
  const int total = 3*X + 4*W;
  int idx = blockIdx.x * blockDim.x + threadIdx.x;
  int stride = gridDim.x * blockDim.x;
  for (int i = idx; i < total; i += stride) {
    const float* src; int off;
    if      (i <   X)     { src = s0; off = i; }
    else if (i < 2*X)     { src = s1; off = i - X; }
    else if (i < 3*X)     { src = s2; off = i - 2*X; }
    else if (i < 3*X+W)   { src = s3; off = i - 3*X; }
    else if (i < 3*X+2*W) { src = s4; off = i - (3*X+W); }
    else if (i < 3*X+3*W) { src = s5; off = i - (3*X+2*W); }
    else                  { src = s6; off = i - (3*X+3*W); }
    float4 v = ((const float4*)src)[off];
    f16x4 o;
    o[0] = (_Float16)v.x; o[1] = (_Float16)v.y; o[2] = (_Float16)v.z; o[3] = (_Float16)v.w;
    ((f16x4*)dst)[i] = o;
  }
}

// ---------------- NT GEMM: C = A[M,K] * B[N,K]^T + bias (m97 structure) ----------------
template<bool OUTF32>
__global__ __launch_bounds__(256)
void gemm_bt(const f16* __restrict__ A, const f16* __restrict__ Bw,
             const float* __restrict__ bias, float* __restrict__ Cf,
             f16* __restrict__ Ch, int M, int N, int K)
{
  __shared__ __align__(16) f16 As[128*32];
  __shared__ __align__(16) f16 Bs[128*32];
  const int t = threadIdx.x;
  const int l = t & 63, w = t >> 6;
  const int wr = w >> 1, wc = w & 1;
  const int m0 = blockIdx.y * 128, n0 = blockIdx.x * 128;

  f32x4 acc[4][4];
  #pragma unroll
  for (int i = 0; i < 4; ++i)
    #pragma unroll
    for (int j = 0; j < 4; ++j)
      acc[i][j] = f32x4{0.f, 0.f, 0.f, 0.f};

  const int off0 = (w*2+0)*1024 + l*16;
  const int off1 = (w*2+1)*1024 + l*16;
  const int row0 = off0 >> 6, k0 = (off0 & 63) >> 1;
  const int row1 = off1 >> 6, k1 = (off1 & 63) >> 1;
  const f16* a0 = A  + (size_t)(m0+row0)*K + k0;
  const f16* a1 = A  + (size_t)(m0+row1)*K + k1;
  const f16* b0 = Bw + (size_t)(n0+row0)*K + k0;
  const f16* b1 = Bw + (size_t)(n0+row1)*K + k1;
  f16* As0 = As + off0/2; f16* As1 = As + off1/2;
  f16* Bs0 = Bs + off0/2; f16* Bs1 = Bs + off1/2;

  const int aoff = (wr*64 + (l&15))*32 + ((l>>4)<<3);
  const int boff = (wc*64 + (l&15))*32 + ((l>>4)<<3);

  for (int kt = 0; kt < K; kt += 32) {
    __syncthreads();
    gld16(a0 + kt, As0);
    gld16(a1 + kt, As1);
    gld16(b0 + kt, Bs0);
    gld16(b1 + kt, Bs1);
    __syncthreads();
    f16x8 af[4], bf[4];
    #pragma unroll
    for (int i = 0; i < 4; ++i) af[i] = *(const f16x8*)(As + aoff + i*512);
    #pragma unroll
    for (int j = 0; j < 4; ++j) bf[j] = *(const f16x8*)(Bs + boff + j*512);
    #pragma unroll
    for (int i = 0; i < 4; ++i)
      #pragma unroll
      for (int j = 0; j < 4; ++j)
        acc[i][j] = __builtin_amdgcn_mfma_f32_16x16x32_f16(af[i], bf[j], acc[i][j], 0, 0, 0);
  }

  #pragma unroll
  for (int j = 0; j < 4; ++j) {
    const int col = n0 + wc*64 + j*16 + (l & 15);
    const float bb = bias[col];
    #pragma unroll
    for (int i = 0; i < 4; ++i) {
      const int rowb = m0 + wr*64 + i*16 + ((l>>4)<<2);
      #pragma unroll
      for (int r = 0; r < 4; ++r) {
        float v = acc[i][j][r] + bb;
        if constexpr (OUTF32) Cf[(size_t)(rowb+r)*N + col] = v;
        else                  Ch[(size_t)(rowb+r)*N + col] = (f16)v;
      }
    }
  }
}

// ---------------- flash attention: R8 structure + V lane=key staging + plswap P-pack + setprio ----------------
// Single-buffer (R8-proven). K via gld_lds (proven). V lane=key remap: lane l stages
// V[key=l][d=w*16..w*16+15] -> per-write-instr banks span all 32 (2 lanes/bank = free).
// Cross-half reductions: __shfl_xor(x,32) (proven; permlane a==b variant miscompiles).
__global__ __launch_bounds__(256, 4)
void attn_kernel(const f16* __restrict__ Q, const f16* __restrict__ K,
                 const f16* __restrict__ V, f16* __restrict__ O)
{
  __shared__ __align__(16) f16 S_lds[8192];   // [0,4096): K tile, [4096,8192): Vt tile

  const int t = threadIdx.x, l = t & 63, w = t >> 6;
  const int lq = l & 31, hi = l >> 5;

  // XCD-bijective swizzle: all 16 q-tiles of one bh on one XCD
  const int lin = blockIdx.x + (blockIdx.y << 4);
  const int xcd = lin & 7, jj = lin >> 3;
  const int bh = xcd * 8 + (jj >> 4);
  const int qt = jj & 15;
  const int b = bh >> 4, h = bh & 15;
  const size_t base = (size_t)b * NS * NE + (size_t)h * ND;
  const int q = qt*128 + w*32 + lq;

  // Q B-fragments
  f16x8 bq[4];
  #pragma unroll
  for (int ks = 0; ks < 4; ++ks)
    bq[ks] = *(const f16x8*)&Q[base + (size_t)q*NE + ks*16 + hi*8];
  asm volatile("s_waitcnt vmcnt(0)" ::: "memory");

  f32x16 o[2];
  #pragma unroll
  for (int dt = 0; dt < 2; ++dt)
    #pragma unroll
    for (int r = 0; r < 16; ++r) o[dt][r] = 0.f;
  float m2 = -3e38f, lsum = 0.f;
  const float K2 = 0.125f * 1.44269504089f;

  // ---- K staging src (inverse-permuted; proven R8) ----
  const int krow0 = w*16 + (l>>3);
  const int kgran = ((l&7) ^ (l>>3)) * 8;
  const f16* kSrc0 = K + base + (size_t)krow0*NE + kgran;
  const f16* kSrc1 = kSrc0 + (size_t)8*NE;
  f16* kDst0 = &S_lds[0] + (w*2+0)*512 + l*8;
  f16* kDst1 = &S_lds[0] + (w*2+1)*512 + l*8;

  // ---- V staging src: lane = key row l, d-chunk = w*16..w*16+15 (conflict-free writes) ----
  const f16* vSrc = V + base + (size_t)l*NE + w*16;
  const char* ksb = (const char*)&S_lds[0];
  char* vtb = (char*)&S_lds[4096];

  const size_t tileAdv = (size_t)64 * NE;

  for (int it = 0; it < 32; ++it) {
    const size_t g = (size_t)it * tileAdv;
    __syncthreads();
    gld16(kSrc0 + g, kDst0);
    gld16(kSrc1 + g, kDst1);
    {
      f16x8 va = *(const f16x8*)(vSrc + g);
      f16x8 vb = *(const f16x8*)(vSrc + g + 8);
      #pragma unroll
      for (int i = 0; i < 8; ++i) {
        const int d0 = w*16 + i, d1 = w*16 + 8 + i;   // d&7 == i&7 for both
        *(f16*)(vtb + ((d0*128 + l*2) ^ ((i & 7) << 4))) = va[i];
        *(f16*)(vtb + ((d1*128 + l*2) ^ ((i & 7) << 4))) = vb[i];
      }
    }
    __syncthreads();   // drains vmcnt(0) (K DMA) + lgkmcnt (V writes)

    // ---- S^T = K * Q^T ----
    f32x16 s[2];
    #pragma unroll
    for (int ct = 0; ct < 2; ++ct)
      #pragma unroll
      for (int r = 0; r < 16; ++r) s[ct][r] = 0.f;
    __builtin_amdgcn_s_setprio(1);
    #pragma unroll
    for (int ct = 0; ct < 2; ++ct) {
      const int krow = ct*32 + lq;
      const int rswz = (krow & 7) << 4;
      #pragma unroll
      for (int ks = 0; ks < 4; ++ks) {
        f16x8 ak = *(const f16x8*)(ksb + ((krow*128 + ks*32 + hi*16) ^ rswz));
        s[ct] = __builtin_amdgcn_mfma_f32_32x32x16_f16(ak, bq[ks], s[ct], 0, 0, 0);
      }
    }
    __builtin_amdgcn_s_setprio(0);

    // ---- in-lane online softmax (base-2), shfl cross-half (proven) ----
    float mx = fmaxf(s[0][0], s[1][0]);
    #pragma unroll
    for (int r = 1; r < 16; ++r) mx = fmaxf(mx, fmaxf(s[0][r], s[1][r]));
    mx *= K2;
    mx = fmaxf(mx, __shfl_xor(mx, 32));
    const float mnew = fmaxf(m2, mx);
    const float alpha = __builtin_amdgcn_exp2f(m2 - mnew);
    m2 = mnew;
    float ps = 0.f;
    #pragma unroll
    for (int ct = 0; ct < 2; ++ct)
      #pragma unroll
      for (int r = 0; r < 16; ++r) {
        float p = __builtin_amdgcn_exp2f(s[ct][r]*K2 - m2);
        s[ct][r] = p;
        ps += p;
      }
    lsum = lsum*alpha + ps;     // per-lane partial; cross-half combine at end
    #pragma unroll
    for (int dt = 0; dt < 2; ++dt)
      #pragma unroll
      for (int r = 0; r < 16; ++r) o[dt][r] *= alpha;

    // ---- pack P, build PV B-operands via plswap (distinct values: proven R5==R6) ----
    f16x8 pa[4];
    #pragma unroll
    for (int ct = 0; ct < 2; ++ct) {
      unsigned wd[8];
      #pragma unroll
      for (int m = 0; m < 4; ++m)
        #pragma unroll
        for (int hh = 0; hh < 2; ++hh)
          wd[m*2 + hh] = cvt2h(s[ct][4*m + 2*hh], s[ct][4*m + 2*hh + 1]);
      #pragma unroll
      for (int ks2 = 0; ks2 < 2; ++ks2) {
        unsigned a0 = wd[(2*ks2)*2 + 0], b0 = wd[(2*ks2+1)*2 + 0];
        unsigned a1 = wd[(2*ks2)*2 + 1], b1 = wd[(2*ks2+1)*2 + 1];
        plswap(a0, b0);
        plswap(a1, b1);
        union { unsigned u[4]; f16x8 v; } pp;
        pp.u[0] = a0; pp.u[1] = a1; pp.u[2] = b0; pp.u[3] = b1;
        pa[ct*2 + ks2] = pp.v;
      }
    }

    // ---- O^T += V^T * P ----
    __builtin_amdgcn_s_setprio(1);
    #pragma unroll
    for (int ks = 0; ks < 4; ++ks)
      #pragma unroll
      for (int dt = 0; dt < 2; ++dt) {
        const int drow = dt*32 + lq;
        f16x8 av = *(const f16x8*)(vtb + ((drow*128 + ks*32 + hi*16) ^ ((drow & 7) << 4)));
        o[dt] = __builtin_amdgcn_mfma_f32_32x32x16_f16(av, pa[ks], o[dt], 0, 0, 0);
      }
    __builtin_amdgcn_s_setprio(0);
  }

  // ---- epilogue: cross-half lsum combine (shfl, proven), normalize, store ----
  const float lt = lsum + __shfl_xor(lsum, 32);
  const float linv = 1.0f / lt;
  #pragma unroll
  for (int dt = 0; dt < 2; ++dt)
    #pragma unroll
    for (int m = 0; m < 4; ++m) {
      u32x2 st;
      st.x = cvt2h(o[dt][4*m+0]*linv, o[dt][4*m+1]*linv);
      st.y = cvt2h(o[dt][4*m+2]*linv, o[dt][4*m+3]*linv);
      const int d = dt*32 + 8*m + 4*hi;
      *(u32x2*)&O[base + (size_t)q*NE + d] = st;
    }
}

// ---------------- launch ----------------
extern "C" void kernel_launch(void* const* d_in, const int* in_sizes, int n_in,
                              void* d_out, int out_size, void* d_ws, size_t ws_size,
                              hipStream_t stream)
{
  const float* q_in = (const float*)d_in[0];
  const float* k_in = (const float*)d_in[1];
  const float* v_in = (const float*)d_in[2];
  const float* Wq = (const float*)d_in[3];
  const float* bq = (const float*)d_in[4];
  const float* Wk = (const float*)d_in[5];
  const float* bk = (const float*)d_in[6];
  const float* Wv = (const float*)d_in[7];
  const float* bv = (const float*)d_in[8];
  const float* Wo = (const float*)d_in[9];
  const float* bo = (const float*)d_in[10];

  char* ws = (char*)d_ws;
  f16* Xq   = (f16*)(ws + 0);
  f16* Xk   = (f16*)(ws + 16777216);
  f16* Xv   = (f16*)(ws + 33554432);
  f16* Wq16 = (f16*)(ws + 50331648);
  f16* Wk16 = (f16*)(ws + 52428800);
  f16* Wv16 = (f16*)(ws + 54525952);
  f16* Wo16 = (f16*)(ws + 56623104);
  f16* Qp   = (f16*)(ws + 58720256);
  f16* Kp   = (f16*)(ws + 75497472);
  f16* Vp   = (f16*)(ws + 92274688);
  f16* Op   = (f16*)(ws + 109051904);

  cvt_all<<<2048, 256, 0, stream>>>(q_in, k_in, v_in, Wq, Wk, Wv, Wo, Xq);

  dim3 gg(8, 64);
  gemm_bt<false><<<gg, 256, 0, stream>>>(Xq, Wq16, bq, nullptr, Qp, NM, NE, NE);
  gemm_bt<false><<<gg, 256, 0, stream>>>(Xk, Wk16, bk, nullptr, Kp, NM, NE, NE);
  gemm_bt<false><<<gg, 256, 0, stream>>>(Xv, Wv16, bv, nullptr, Vp, NM, NE, NE);

  attn_kernel<<<dim3(16, 64), 256, 0, stream>>>(Qp, Kp, Vp, Op);

  gemm_bt<true><<<gg, 256, 0, stream>>>(Op, Wo16, bo, (float*)d_out, nullptr, NM, NE, NE);
}

// Round 12
// 263.834 us; speedup vs baseline: 1.7056x; 1.0086x over previous
//
#include <hip/hip_runtime.h>

typedef _Float16 f16;
typedef __attribute__((ext_vector_type(2))) __fp16 fp16x2_raw;
typedef __attribute__((ext_vector_type(4))) _Float16 f16x4;
typedef __attribute__((ext_vector_type(8))) _Float16 f16x8;
typedef __attribute__((ext_vector_type(4))) float f32x4;
typedef __attribute__((ext_vector_type(16))) float f32x16;
typedef __attribute__((ext_vector_type(2))) unsigned int u32x2;

#define NB 4
#define NS 2048
#define NE 1024
#define NH 16
#define ND 64
#define NM (NB*NS)   // 8192 tokens

__device__ __forceinline__ void gld16(const void* g, void* l) {
  __builtin_amdgcn_global_load_lds((const __attribute__((address_space(1))) unsigned int*)g,
                                   (__attribute__((address_space(3))) unsigned int*)l, 16, 0, 0);
}

// pack two f32 -> one u32 of 2 f16 (v_cvt_pkrtz_f16_f32)
__device__ __forceinline__ unsigned cvt2h(float a, float b) {
  fp16x2_raw r = __builtin_amdgcn_cvt_pkrtz(a, b);
  return __builtin_bit_cast(unsigned, r);
}

// proven (R5==R6, distinct-value operands so no reg-coalesce hazard):
// new_a[l] = l<32 ? a[l] : b[l-32]; new_b[l] = l<32 ? a[l+32] : b[l]
__device__ __forceinline__ void plswap(unsigned& a, unsigned& b) {
  asm volatile("v_permlane32_swap_b32 %0, %1" : "+v"(a), "+v"(b));
}
// NOTE: a==b plswap variant miscompiles (R9/R10 — allocator coalesces equal-valued
// operands into one VGPR). Cross-half reductions use proven __shfl_xor(x,32).

// ---------------- fused f32 -> f16 convert ----------------
__global__ __launch_bounds__(256) void cvt_all(const float* __restrict__ s0, const float* __restrict__ s1,
                                               const float* __restrict__ s2, const float* __restrict__ s3,
                                               const float* __restrict__ s4, const float* __restrict__ s5,
                                               const float* __restrict__ s6, f16* __restrict__ dst) {
  const int X = NM*NE/4;
  const int W = NE*NE/4;
  const int total = 3*X + 4*W;
  int idx = blockIdx.x * blockDim.x + threadIdx.x;
  int stride = gridDim.x * blockDim.x;
  for (int i = idx; i < total; i += stride) {
    const float* src; int off;
    if      (i <   X)     { src = s0; off = i; }
    else if (i < 2*X)     { src = s1; off = i - X; }
    else if (i < 3*X)     { src = s2; off = i - 2*X; }
    else if (i < 3*X+W)   { src = s3; off = i - 3*X; }
    else if (i < 3*X+2*W) { src = s4; off = i - (3*X+W); }
    else if (i < 3*X+3*W) { src = s5; off = i - (3*X+2*W); }
    else                  { src = s6; off = i - (3*X+3*W); }
    float4 v = ((const float4*)src)[off];
    f16x4 o;
    o[0] = (_Float16)v.x; o[1] = (_Float16)v.y; o[2] = (_Float16)v.z; o[3] = (_Float16)v.w;
    ((f16x4*)dst)[i] = o;
  }
}

// ---------------- NT GEMM: C = A[M,K] * B[N,K]^T + bias (m97 structure) ----------------
template<bool OUTF32>
__global__ __launch_bounds__(256)
void gemm_bt(const f16* __restrict__ A, const f16* __restrict__ Bw,
             const float* __restrict__ bias, float* __restrict__ Cf,
             f16* __restrict__ Ch, int M, int N, int K)
{
  __shared__ __align__(16) f16 As[128*32];
  __shared__ __align__(16) f16 Bs[128*32];
  const int t = threadIdx.x;
  const int l = t & 63, w = t >> 6;
  const int wr = w >> 1, wc = w & 1;
  const int m0 = blockIdx.y * 128, n0 = blockIdx.x * 128;

  f32x4 acc[4][4];
  #pragma unroll
  for (int i = 0; i < 4; ++i)
    #pragma unroll
    for (int j = 0; j < 4; ++j)
      acc[i][j] = f32x4{0.f, 0.f, 0.f, 0.f};

  const int off0 = (w*2+0)*1024 + l*16;
  const int off1 = (w*2+1)*1024 + l*16;
  const int row0 = off0 >> 6, k0 = (off0 & 63) >> 1;
  const int row1 = off1 >> 6, k1 = (off1 & 63) >> 1;
  const f16* a0 = A  + (size_t)(m0+row0)*K + k0;
  const f16* a1 = A  + (size_t)(m0+row1)*K + k1;
  const f16* b0 = Bw + (size_t)(n0+row0)*K + k0;
  const f16* b1 = Bw + (size_t)(n0+row1)*K + k1;
  f16* As0 = As + off0/2; f16* As1 = As + off1/2;
  f16* Bs0 = Bs + off0/2; f16* Bs1 = Bs + off1/2;

  const int aoff = (wr*64 + (l&15))*32 + ((l>>4)<<3);
  const int boff = (wc*64 + (l&15))*32 + ((l>>4)<<3);

  for (int kt = 0; kt < K; kt += 32) {
    __syncthreads();
    gld16(a0 + kt, As0);
    gld16(a1 + kt, As1);
    gld16(b0 + kt, Bs0);
    gld16(b1 + kt, Bs1);
    __syncthreads();
    f16x8 af[4], bf[4];
    #pragma unroll
    for (int i = 0; i < 4; ++i) af[i] = *(const f16x8*)(As + aoff + i*512);
    #pragma unroll
    for (int j = 0; j < 4; ++j) bf[j] = *(const f16x8*)(Bs + boff + j*512);
    #pragma unroll
    for (int i = 0; i < 4; ++i)
      #pragma unroll
      for (int j = 0; j < 4; ++j)
        acc[i][j] = __builtin_amdgcn_mfma_f32_16x16x32_f16(af[i], bf[j], acc[i][j], 0, 0, 0);
  }

  #pragma unroll
  for (int j = 0; j < 4; ++j) {
    const int col = n0 + wc*64 + j*16 + (l & 15);
    const float bb = bias[col];
    #pragma unroll
    for (int i = 0; i < 4; ++i) {
      const int rowb = m0 + wr*64 + i*16 + ((l>>4)<<2);
      #pragma unroll
      for (int r = 0; r < 4; ++r) {
        float v = acc[i][j][r] + bb;
        if constexpr (OUTF32) Cf[(size_t)(rowb+r)*N + col] = v;
        else                  Ch[(size_t)(rowb+r)*N + col] = (f16)v;
      }
    }
  }
}

// ---------------- flash attention: R11 + 2-phase double-buffer ----------------
// LDS 32KB: buf b at f16-offset b*8192: K [64 key][64 d] XOR-swz (gld_lds, inverse-permuted src),
// Vt [64 d][64 key] XOR-swz at +4096 (lane=key staging, conflict-free writes).
// Per iter: issue next-tile loads -> compute current -> vmcnt(0) -> Vt writes -> one barrier.
__global__ __launch_bounds__(256, 4)
void attn_kernel(const f16* __restrict__ Q, const f16* __restrict__ K,
                 const f16* __restrict__ V, f16* __restrict__ O)
{
  __shared__ __align__(16) f16 S_lds[16384];

  const int t = threadIdx.x, l = t & 63, w = t >> 6;
  const int lq = l & 31, hi = l >> 5;

  // XCD-bijective swizzle: all 16 q-tiles of one bh on one XCD
  const int lin = blockIdx.x + (blockIdx.y << 4);
  const int xcd = lin & 7, jj = lin >> 3;
  const int bh = xcd * 8 + (jj >> 4);
  const int qt = jj & 15;
  const int b = bh >> 4, h = bh & 15;
  const size_t base = (size_t)b * NS * NE + (size_t)h * ND;
  const int q = qt*128 + w*32 + lq;

  // Q B-fragments
  f16x8 bq[4];
  #pragma unroll
  for (int ks = 0; ks < 4; ++ks)
    bq[ks] = *(const f16x8*)&Q[base + (size_t)q*NE + ks*16 + hi*8];
  asm volatile("s_waitcnt vmcnt(0)" ::: "memory");

  f32x16 o[2];
  #pragma unroll
  for (int dt = 0; dt < 2; ++dt)
    #pragma unroll
    for (int r = 0; r < 16; ++r) o[dt][r] = 0.f;
  float m2 = -3e38f, lsum = 0.f;
  const float K2 = 0.125f * 1.44269504089f;

  // ---- K staging src (inverse-permuted; proven) ----
  const int krow0 = w*16 + (l>>3);
  const int kgran = ((l&7) ^ (l>>3)) * 8;
  const f16* kSrc0 = K + base + (size_t)krow0*NE + kgran;
  const f16* kSrc1 = kSrc0 + (size_t)8*NE;
  // ---- V staging src: lane = key row l, d-chunk = w*16..w*16+15 (proven) ----
  const f16* vSrc = V + base + (size_t)l*NE + w*16;

  const size_t tileAdv = (size_t)64 * NE;
  const int kd0 = (w*2+0)*512 + l*8;
  const int kd1 = (w*2+1)*512 + l*8;

  // ================= prologue: stage tile 0 into buf 0 =================
  f16x8 va, vb;
  {
    gld16(kSrc0, &S_lds[0] + kd0);
    gld16(kSrc1, &S_lds[0] + kd1);
    va = *(const f16x8*)(vSrc);
    vb = *(const f16x8*)(vSrc + 8);
    asm volatile("s_waitcnt vmcnt(0)" ::: "memory");
    char* vt0 = (char*)&S_lds[4096];
    #pragma unroll
    for (int i = 0; i < 8; ++i) {
      const int d0 = w*16 + i, d1 = w*16 + 8 + i;   // d&7 == i&7 for both
      *(f16*)(vt0 + ((d0*128 + l*2) ^ ((i & 7) << 4))) = va[i];
      *(f16*)(vt0 + ((d1*128 + l*2) ^ ((i & 7) << 4))) = vb[i];
    }
  }
  __syncthreads();

  for (int it = 0; it < 32; ++it) {
    const int cur = it & 1, nb = cur ^ 1;
    const char* ksb = (const char*)(&S_lds[cur*8192]);
    const char* vtb = (const char*)(&S_lds[cur*8192 + 4096]);

    // ---- issue next-tile staging loads (overlap with this tile's compute) ----
    if (it < 31) {
      const size_t g = (size_t)(it+1) * tileAdv;
      gld16(kSrc0 + g, &S_lds[nb*8192] + kd0);
      gld16(kSrc1 + g, &S_lds[nb*8192] + kd1);
      va = *(const f16x8*)(vSrc + g);
      vb = *(const f16x8*)(vSrc + g + 8);
    }

    // ---- S^T = K * Q^T ----
    f32x16 s[2];
    #pragma unroll
    for (int ct = 0; ct < 2; ++ct)
      #pragma unroll
      for (int r = 0; r < 16; ++r) s[ct][r] = 0.f;
    __builtin_amdgcn_s_setprio(1);
    #pragma unroll
    for (int ct = 0; ct < 2; ++ct) {
      const int krow = ct*32 + lq;
      const int rswz = (krow & 7) << 4;
      #pragma unroll
      for (int ks = 0; ks < 4; ++ks) {
        f16x8 ak = *(const f16x8*)(ksb + ((krow*128 + ks*32 + hi*16) ^ rswz));
        s[ct] = __builtin_amdgcn_mfma_f32_32x32x16_f16(ak, bq[ks], s[ct], 0, 0, 0);
      }
    }
    __builtin_amdgcn_s_setprio(0);

    // ---- in-lane online softmax (base-2), shfl cross-half (proven) ----
    float mx = fmaxf(s[0][0], s[1][0]);
    #pragma unroll
    for (int r = 1; r < 16; ++r) mx = fmaxf(mx, fmaxf(s[0][r], s[1][r]));
    mx *= K2;
    mx = fmaxf(mx, __shfl_xor(mx, 32));
    const float mnew = fmaxf(m2, mx);
    const float alpha = __builtin_amdgcn_exp2f(m2 - mnew);
    m2 = mnew;
    float ps = 0.f;
    #pragma unroll
    for (int ct = 0; ct < 2; ++ct)
      #pragma unroll
      for (int r = 0; r < 16; ++r) {
        float p = __builtin_amdgcn_exp2f(s[ct][r]*K2 - m2);
        s[ct][r] = p;
        ps += p;
      }
    lsum = lsum*alpha + ps;     // per-lane partial; cross-half combine at end
    #pragma unroll
    for (int dt = 0; dt < 2; ++dt)
      #pragma unroll
      for (int r = 0; r < 16; ++r) o[dt][r] *= alpha;

    // ---- pack P, build PV B-operands via plswap (distinct values: proven) ----
    f16x8 pa[4];
    #pragma unroll
    for (int ct = 0; ct < 2; ++ct) {
      unsigned wd[8];
      #pragma unroll
      for (int m = 0; m < 4; ++m)
        #pragma unroll
        for (int hh = 0; hh < 2; ++hh)
          wd[m*2 + hh] = cvt2h(s[ct][4*m + 2*hh], s[ct][4*m + 2*hh + 1]);
      #pragma unroll
      for (int ks2 = 0; ks2 < 2; ++ks2) {
        unsigned a0 = wd[(2*ks2)*2 + 0], b0 = wd[(2*ks2+1)*2 + 0];
        unsigned a1 = wd[(2*ks2)*2 + 1], b1 = wd[(2*ks2+1)*2 + 1];
        plswap(a0, b0);
        plswap(a1, b1);
        union { unsigned u[4]; f16x8 v; } pp;
        pp.u[0] = a0; pp.u[1] = a1; pp.u[2] = b0; pp.u[3] = b1;
        pa[ct*2 + ks2] = pp.v;
      }
    }

    // ---- O^T += V^T * P ----
    __builtin_amdgcn_s_setprio(1);
    #pragma unroll
    for (int ks = 0; ks < 4; ++ks)
      #pragma unroll
      for (int dt = 0; dt < 2; ++dt) {
        const int drow = dt*32 + lq;
        f16x8 av = *(const f16x8*)(vtb + ((drow*128 + ks*32 + hi*16) ^ ((drow & 7) << 4)));
        o[dt] = __builtin_amdgcn_mfma_f32_32x32x16_f16(av, pa[ks], o[dt], 0, 0, 0);
      }
    __builtin_amdgcn_s_setprio(0);

    // ---- finish staging next tile: drain loads, write Vt, single barrier ----
    if (it < 31) {
      asm volatile("s_waitcnt vmcnt(0)" ::: "memory");
      char* vtn = (char*)(&S_lds[nb*8192 + 4096]);
      #pragma unroll
      for (int i = 0; i < 8; ++i) {
        const int d0 = w*16 + i, d1 = w*16 + 8 + i;
        *(f16*)(vtn + ((d0*128 + l*2) ^ ((i & 7) << 4))) = va[i];
        *(f16*)(vtn + ((d1*128 + l*2) ^ ((i & 7) << 4))) = vb[i];
      }
      __syncthreads();
    }
  }

  // ---- epilogue: cross-half lsum combine (shfl, proven), normalize, store ----
  const float lt = lsum + __shfl_xor(lsum, 32);
  const float linv = 1.0f / lt;
  #pragma unroll
  for (int dt = 0; dt < 2; ++dt)
    #pragma unroll
    for (int m = 0; m < 4; ++m) {
      u32x2 st;
      st.x = cvt2h(o[dt][4*m+0]*linv, o[dt][4*m+1]*linv);
      st.y = cvt2h(o[dt][4*m+2]*linv, o[dt][4*m+3]*linv);
      const int d = dt*32 + 8*m + 4*hi;
      *(u32x2*)&O[base + (size_t)q*NE + d] = st;
    }
}

// ---------------- launch ----------------
extern "C" void kernel_launch(void* const* d_in, const int* in_sizes, int n_in,
                              void* d_out, int out_size, void* d_ws, size_t ws_size,
                              hipStream_t stream)
{
  const float* q_in = (const float*)d_in[0];
  const float* k_in = (const float*)d_in[1];
  const float* v_in = (const float*)d_in[2];
  const float* Wq = (const float*)d_in[3];
  const float* bq = (const float*)d_in[4];
  const float* Wk = (const float*)d_in[5];
  const float* bk = (const float*)d_in[6];
  const float* Wv = (const float*)d_in[7];
  const float* bv = (const float*)d_in[8];
  const float* Wo = (const float*)d_in[9];
  const float* bo = (const float*)d_in[10];

  char* ws = (char*)d_ws;
  f16* Xq   = (f16*)(ws + 0);
  f16* Xk   = (f16*)(ws + 16777216);
  f16* Xv   = (f16*)(ws + 33554432);
  f16* Wq16 = (f16*)(ws + 50331648);
  f16* Wk16 = (f16*)(ws + 52428800);
  f16* Wv16 = (f16*)(ws + 54525952);
  f16* Wo16 = (f16*)(ws + 56623104);
  f16* Qp   = (f16*)(ws + 58720256);
  f16* Kp   = (f16*)(ws + 75497472);
  f16* Vp   = (f16*)(ws + 92274688);
  f16* Op   = (f16*)(ws + 109051904);

  cvt_all<<<2048, 256, 0, stream>>>(q_in, k_in, v_in, Wq, Wk, Wv, Wo, Xq);

  dim3 gg(8, 64);
  gemm_bt<false><<<gg, 256, 0, stream>>>(Xq, Wq16, bq, nullptr, Qp, NM, NE, NE);
  gemm_bt<false><<<gg, 256, 0, stream>>>(Xk, Wk16, bk, nullptr, Kp, NM, NE, NE);
  gemm_bt<false><<<gg, 256, 0, stream>>>(Xv, Wv16, bv, nullptr, Vp, NM, NE, NE);

  attn_kernel<<<dim3(16, 64), 256, 0, stream>>>(Qp, Kp, Vp, Op);

  gemm_bt<true><<<gg, 256, 0, stream>>>(Op, Wo16, bo, (float*)d_out, nullptr, NM, NE, NE);
}

// Round 15
// 252.934 us; speedup vs baseline: 1.7791x; 1.0431x over previous
//
#include <hip/hip_runtime.h>

typedef _Float16 f16;
typedef __attribute__((ext_vector_type(2))) __fp16 fp16x2_raw;
typedef __attribute__((ext_vector_type(4))) _Float16 f16x4;
typedef __attribute__((ext_vector_type(8))) _Float16 f16x8;
typedef __attribute__((ext_vector_type(4))) float f32x4;
typedef __attribute__((ext_vector_type(16))) float f32x16;
typedef __attribute__((ext_vector_type(2))) unsigned int u32x2;

#define NB 4
#define NS 2048
#define NE 1024
#define NH 16
#define ND 64
#define NM (NB*NS)   // 8192 tokens

__device__ __forceinline__ void gld16(const void* g, void* l) {
  __builtin_amdgcn_global_load_lds((const __attribute__((address_space(1))) unsigned int*)g,
                                   (__attribute__((address_space(3))) unsigned int*)l, 16, 0, 0);
}

// pack two f32 -> one u32 of 2 f16 (v_cvt_pkrtz_f16_f32)
__device__ __forceinline__ unsigned cvt2h(float a, float b) {
  fp16x2_raw r = __builtin_amdgcn_cvt_pkrtz(a, b);
  return __builtin_bit_cast(unsigned, r);
}

// proven (R5==R6, distinct-value operands so no reg-coalesce hazard):
// new_a[l] = l<32 ? a[l] : b[l-32]; new_b[l] = l<32 ? a[l+32] : b[l]
__device__ __forceinline__ void plswap(unsigned& a, unsigned& b) {
  asm volatile("v_permlane32_swap_b32 %0, %1" : "+v"(a), "+v"(b));
}
// NOTE: a==b plswap variant miscompiles (R9/R10 — allocator coalesces equal-valued
// operands into one VGPR). Cross-half reductions use proven __shfl_xor(x,32).

// ---------------- fused f32 -> f16 convert ----------------
__global__ __launch_bounds__(256) void cvt_all(const float* __restrict__ s0, const float* __restrict__ s1,
                                               const float* __restrict__ s2, const float* __restrict__ s3,
                                               const float* __restrict__ s4, const float* __restrict__ s5,
                                               const float* __restrict__ s6, f16* __restrict__ dst) {
  const int X = NM*NE/4;
  const int W = NE*NE/4;
  const int total = 3*X + 4*W;
  int idx = blockIdx.x * blockDim.x + threadIdx.x;
  int stride = gridDim.x * blockDim.x;
  for (int i = idx; i < total; i += stride) {
    const float* src; int off;
    if      (i <   X)     { src = s0; off = i; }
    else if (i < 2*X)     { src = s1; off = i - X; }
    else if (i < 3*X)     { src = s2; off = i - 2*X; }
    else if (i < 3*X+W)   { src = s3; off = i - 3*X; }
    else if (i < 3*X+2*W) { src = s4; off = i - (3*X+W); }
    else if (i < 3*X+3*W) { src = s5; off = i - (3*X+2*W); }
    else                  { src = s6; off = i - (3*X+3*W); }
    float4 v = ((const float4*)src)[off];
    f16x4 o;
    o[0] = (_Float16)v.x; o[1] = (_Float16)v.y; o[2] = (_Float16)v.z; o[3] = (_Float16)v.w;
    ((f16x4*)dst)[i] = o;
  }
}

// ---------------- NT GEMM: C = A[M,K] * B[N,K]^T + bias ----------------
// R12-proven 2-barrier m97 structure (R13's single-barrier dbuf raced post-timing — reverted).
// + XCD-bijective swizzle: m_blk == hw_id mod 8, so all 8 n-blocks sharing an
// A-row-panel land on ONE XCD (A HBM traffic /8).
template<bool OUTF32>
__global__ __launch_bounds__(256)
void gemm_bt(const f16* __restrict__ A, const f16* __restrict__ Bw,
             const float* __restrict__ bias, float* __restrict__ Cf,
             f16* __restrict__ Ch, int M, int N, int K)
{
  __shared__ __align__(16) f16 As[128*32];
  __shared__ __align__(16) f16 Bs[128*32];
  const int t = threadIdx.x;
  const int l = t & 63, w = t >> 6;
  const int wr = w >> 1, wc = w & 1;

  // XCD swizzle: id = (xcd, slot); m_blk = (slot>>3)*8 + xcd, n_blk = slot&7 (bijective, nwg=512)
  const int id = blockIdx.x + blockIdx.y * gridDim.x;
  const int xcd = id & 7, slot = id >> 3;
  const int m0 = (((slot >> 3) << 3) | xcd) * 128;
  const int n0 = (slot & 7) * 128;

  f32x4 acc[4][4];
  #pragma unroll
  for (int i = 0; i < 4; ++i)
    #pragma unroll
    for (int j = 0; j < 4; ++j)
      acc[i][j] = f32x4{0.f, 0.f, 0.f, 0.f};

  const int off0 = (w*2+0)*1024 + l*16;
  const int off1 = (w*2+1)*1024 + l*16;
  const int row0 = off0 >> 6, k0 = (off0 & 63) >> 1;
  const int row1 = off1 >> 6, k1 = (off1 & 63) >> 1;
  const f16* a0 = A  + (size_t)(m0+row0)*K + k0;
  const f16* a1 = A  + (size_t)(m0+row1)*K + k1;
  const f16* b0 = Bw + (size_t)(n0+row0)*K + k0;
  const f16* b1 = Bw + (size_t)(n0+row1)*K + k1;
  f16* As0 = As + off0/2; f16* As1 = As + off1/2;
  f16* Bs0 = Bs + off0/2; f16* Bs1 = Bs + off1/2;

  const int aoff = (wr*64 + (l&15))*32 + ((l>>4)<<3);
  const int boff = (wc*64 + (l&15))*32 + ((l>>4)<<3);

  for (int kt = 0; kt < K; kt += 32) {
    __syncthreads();
    gld16(a0 + kt, As0);
    gld16(a1 + kt, As1);
    gld16(b0 + kt, Bs0);
    gld16(b1 + kt, Bs1);
    __syncthreads();   // compiler drains vmcnt(0) before barrier
    f16x8 af[4], bf[4];
    #pragma unroll
    for (int i = 0; i < 4; ++i) af[i] = *(const f16x8*)(As + aoff + i*512);
    #pragma unroll
    for (int j = 0; j < 4; ++j) bf[j] = *(const f16x8*)(Bs + boff + j*512);
    #pragma unroll
    for (int i = 0; i < 4; ++i)
      #pragma unroll
      for (int j = 0; j < 4; ++j)
        acc[i][j] = __builtin_amdgcn_mfma_f32_16x16x32_f16(af[i], bf[j], acc[i][j], 0, 0, 0);
  }

  #pragma unroll
  for (int j = 0; j < 4; ++j) {
    const int col = n0 + wc*64 + j*16 + (l & 15);
    const float bb = bias[col];
    #pragma unroll
    for (int i = 0; i < 4; ++i) {
      const int rowb = m0 + wr*64 + i*16 + ((l>>4)<<2);
      #pragma unroll
      for (int r = 0; r < 4; ++r) {
        float v = acc[i][j][r] + bb;
        if constexpr (OUTF32) Cf[(size_t)(rowb+r)*N + col] = v;
        else                  Ch[(size_t)(rowb+r)*N + col] = (f16)v;
      }
    }
  }
}

// ---------------- flash attention: R12 dbuf base + tree-max + split psum + defer-rescale ----------------
__global__ __launch_bounds__(256, 4)
void attn_kernel(const f16* __restrict__ Q, const f16* __restrict__ K,
                 const f16* __restrict__ V, f16* __restrict__ O)
{
  __shared__ __align__(16) f16 S_lds[16384];

  const int t = threadIdx.x, l = t & 63, w = t >> 6;
  const int lq = l & 31, hi = l >> 5;

  // XCD-bijective swizzle: all 16 q-tiles of one bh on one XCD
  const int lin = blockIdx.x + (blockIdx.y << 4);
  const int xcd = lin & 7, jj = lin >> 3;
  const int bh = xcd * 8 + (jj >> 4);
  const int qt = jj & 15;
  const int b = bh >> 4, h = bh & 15;
  const size_t base = (size_t)b * NS * NE + (size_t)h * ND;
  const int q = qt*128 + w*32 + lq;

  // Q B-fragments
  f16x8 bq[4];
  #pragma unroll
  for (int ks = 0; ks < 4; ++ks)
    bq[ks] = *(const f16x8*)&Q[base + (size_t)q*NE + ks*16 + hi*8];
  asm volatile("s_waitcnt vmcnt(0)" ::: "memory");

  f32x16 o[2];
  #pragma unroll
  for (int dt = 0; dt < 2; ++dt)
    #pragma unroll
    for (int r = 0; r < 16; ++r) o[dt][r] = 0.f;
  float m2 = -3e38f, lsum = 0.f;
  const float K2 = 0.125f * 1.44269504089f;

  // ---- K staging src (inverse-permuted; proven) ----
  const int krow0 = w*16 + (l>>3);
  const int kgran = ((l&7) ^ (l>>3)) * 8;
  const f16* kSrc0 = K + base + (size_t)krow0*NE + kgran;
  const f16* kSrc1 = kSrc0 + (size_t)8*NE;
  // ---- V staging src: lane = key row l, d-chunk = w*16..w*16+15 (proven) ----
  const f16* vSrc = V + base + (size_t)l*NE + w*16;

  const size_t tileAdv = (size_t)64 * NE;
  const int kd0 = (w*2+0)*512 + l*8;
  const int kd1 = (w*2+1)*512 + l*8;

  // ================= prologue: stage tile 0 into buf 0 =================
  f16x8 va, vb;
  {
    gld16(kSrc0, &S_lds[0] + kd0);
    gld16(kSrc1, &S_lds[0] + kd1);
    va = *(const f16x8*)(vSrc);
    vb = *(const f16x8*)(vSrc + 8);
    asm volatile("s_waitcnt vmcnt(0)" ::: "memory");
    char* vt0 = (char*)&S_lds[4096];
    #pragma unroll
    for (int i = 0; i < 8; ++i) {
      const int d0 = w*16 + i, d1 = w*16 + 8 + i;   // d&7 == i&7 for both
      *(f16*)(vt0 + ((d0*128 + l*2) ^ ((i & 7) << 4))) = va[i];
      *(f16*)(vt0 + ((d1*128 + l*2) ^ ((i & 7) << 4))) = vb[i];
    }
  }
  __syncthreads();

  for (int it = 0; it < 32; ++it) {
    const int cur = it & 1, nb = cur ^ 1;
    const char* ksb = (const char*)(&S_lds[cur*8192]);
    const char* vtb = (const char*)(&S_lds[cur*8192 + 4096]);

    // ---- issue next-tile staging loads (overlap with this tile's compute) ----
    if (it < 31) {
      const size_t g = (size_t)(it+1) * tileAdv;
      gld16(kSrc0 + g, &S_lds[nb*8192] + kd0);
      gld16(kSrc1 + g, &S_lds[nb*8192] + kd1);
      va = *(const f16x8*)(vSrc + g);
      vb = *(const f16x8*)(vSrc + g + 8);
    }

    // ---- S^T = K * Q^T ----
    f32x16 s[2];
    #pragma unroll
    for (int ct = 0; ct < 2; ++ct)
      #pragma unroll
      for (int r = 0; r < 16; ++r) s[ct][r] = 0.f;
    __builtin_amdgcn_s_setprio(1);
    #pragma unroll
    for (int ct = 0; ct < 2; ++ct) {
      const int krow = ct*32 + lq;
      const int rswz = (krow & 7) << 4;
      #pragma unroll
      for (int ks = 0; ks < 4; ++ks) {
        f16x8 ak = *(const f16x8*)(ksb + ((krow*128 + ks*32 + hi*16) ^ rswz));
        s[ct] = __builtin_amdgcn_mfma_f32_32x32x16_f16(ak, bq[ks], s[ct], 0, 0, 0);
      }
    }
    __builtin_amdgcn_s_setprio(0);

    // ---- pairwise-tree max (depth 5, ILP-rich; exact reassociation of fmax) ----
    float mm[16];
    #pragma unroll
    for (int r = 0; r < 16; ++r) mm[r] = fmaxf(s[0][r], s[1][r]);
    #pragma unroll
    for (int st = 8; st > 0; st >>= 1)
      #pragma unroll
      for (int r = 0; r < st; ++r) mm[r] = fmaxf(mm[r], mm[r+st]);
    float mx = mm[0] * K2;
    mx = fmaxf(mx, __shfl_xor(mx, 32));

    // ---- defer-rescale (T13, THR=8 in log2): skip O-wide rescale when max growth small ----
    if (__any(mx > m2 + 8.0f)) {
      const float mnew = fmaxf(m2, mx);
      const float alpha = __builtin_amdgcn_exp2f(m2 - mnew);
      m2 = mnew;
      lsum *= alpha;
      #pragma unroll
      for (int dt = 0; dt < 2; ++dt)
        #pragma unroll
        for (int r = 0; r < 16; ++r) o[dt][r] *= alpha;
    }

    // ---- exp + 4-way split psum (depth ~8 vs 32) ----
    float ps4[4] = {0.f, 0.f, 0.f, 0.f};
    #pragma unroll
    for (int ct = 0; ct < 2; ++ct)
      #pragma unroll
      for (int r = 0; r < 16; ++r) {
        float p = __builtin_amdgcn_exp2f(s[ct][r]*K2 - m2);
        s[ct][r] = p;
        ps4[r & 3] += p;
      }
    lsum += (ps4[0] + ps4[1]) + (ps4[2] + ps4[3]);

    // ---- pack P, build PV B-operands via plswap (distinct values: proven) ----
    f16x8 pa[4];
    #pragma unroll
    for (int ct = 0; ct < 2; ++ct) {
      unsigned wd[8];
      #pragma unroll
      for (int m = 0; m < 4; ++m)
        #pragma unroll
        for (int hh = 0; hh < 2; ++hh)
          wd[m*2 + hh] = cvt2h(s[ct][4*m + 2*hh], s[ct][4*m + 2*hh + 1]);
      #pragma unroll
      for (int ks2 = 0; ks2 < 2; ++ks2) {
        unsigned a0 = wd[(2*ks2)*2 + 0], b0 = wd[(2*ks2+1)*2 + 0];
        unsigned a1 = wd[(2*ks2)*2 + 1], b1 = wd[(2*ks2+1)*2 + 1];
        plswap(a0, b0);
        plswap(a1, b1);
        union { unsigned u[4]; f16x8 v; } pp;
        pp.u[0] = a0; pp.u[1] = a1; pp.u[2] = b0; pp.u[3] = b1;
        pa[ct*2 + ks2] = pp.v;
      }
    }

    // ---- O^T += V^T * P ----
    __builtin_amdgcn_s_setprio(1);
    #pragma unroll
    for (int ks = 0; ks < 4; ++ks)
      #pragma unroll
      for (int dt = 0; dt < 2; ++dt) {
        const int drow = dt*32 + lq;
        f16x8 av = *(const f16x8*)(vtb + ((drow*128 + ks*32 + hi*16) ^ ((drow & 7) << 4)));
        o[dt] = __builtin_amdgcn_mfma_f32_32x32x16_f16(av, pa[ks], o[dt], 0, 0, 0);
      }
    __builtin_amdgcn_s_setprio(0);

    // ---- finish staging next tile: drain loads, write Vt, single barrier ----
    if (it < 31) {
      asm volatile("s_waitcnt vmcnt(0)" ::: "memory");
      char* vtn = (char*)(&S_lds[nb*8192 + 4096]);
      #pragma unroll
      for (int i = 0; i < 8; ++i) {
        const int d0 = w*16 + i, d1 = w*16 + 8 + i;
        *(f16*)(vtn + ((d0*128 + l*2) ^ ((i & 7) << 4))) = va[i];
        *(f16*)(vtn + ((d1*128 + l*2) ^ ((i & 7) << 4))) = vb[i];
      }
      __syncthreads();
    }
  }

  // ---- epilogue: cross-half lsum combine (shfl, proven), normalize, store ----
  const float lt = lsum + __shfl_xor(lsum, 32);
  const float linv = 1.0f / lt;
  #pragma unroll
  for (int dt = 0; dt < 2; ++dt)
    #pragma unroll
    for (int m = 0; m < 4; ++m) {
      u32x2 st;
      st.x = cvt2h(o[dt][4*m+0]*linv, o[dt][4*m+1]*linv);
      st.y = cvt2h(o[dt][4*m+2]*linv, o[dt][4*m+3]*linv);
      const int d = dt*32 + 8*m + 4*hi;
      *(u32x2*)&O[base + (size_t)q*NE + d] = st;
    }
}

// ---------------- launch ----------------
extern "C" void kernel_launch(void* const* d_in, const int* in_sizes, int n_in,
                              void* d_out, int out_size, void* d_ws, size_t ws_size,
                              hipStream_t stream)
{
  const float* q_in = (const float*)d_in[0];
  const float* k_in = (const float*)d_in[1];
  const float* v_in = (const float*)d_in[2];
  const float* Wq = (const float*)d_in[3];
  const float* bq = (const float*)d_in[4];
  const float* Wk = (const float*)d_in[5];
  const float* bk = (const float*)d_in[6];
  const float* Wv = (const float*)d_in[7];
  const float* bv = (const float*)d_in[8];
  const float* Wo = (const float*)d_in[9];
  const float* bo = (const float*)d_in[10];

  char* ws = (char*)d_ws;
  f16* Xq   = (f16*)(ws + 0);
  f16* Xk   = (f16*)(ws + 16777216);
  f16* Xv   = (f16*)(ws + 33554432);
  f16* Wq16 = (f16*)(ws + 50331648);
  f16* Wk16 = (f16*)(ws + 52428800);
  f16* Wv16 = (f16*)(ws + 54525952);
  f16* Wo16 = (f16*)(ws + 56623104);
  f16* Qp   = (f16*)(ws + 58720256);
  f16* Kp   = (f16*)(ws + 75497472);
  f16* Vp   = (f16*)(ws + 92274688);
  f16* Op   = (f16*)(ws + 109051904);

  cvt_all<<<2048, 256, 0, stream>>>(q_in, k_in, v_in, Wq, Wk, Wv, Wo, Xq);

  dim3 gg(8, 64);
  gemm_bt<false><<<gg, 256, 0, stream>>>(Xq, Wq16, bq, nullptr, Qp, NM, NE, NE);
  gemm_bt<false><<<gg, 256, 0, stream>>>(Xk, Wk16, bk, nullptr, Kp, NM, NE, NE);
  gemm_bt<false><<<gg, 256, 0, stream>>>(Xv, Wv16, bv, nullptr, Vp, NM, NE, NE);

  attn_kernel<<<dim3(16, 64), 256, 0, stream>>>(Qp, Kp, Vp, Op);

  gemm_bt<true><<<gg, 256, 0, stream>>>(Op, Wo16, bo, (float*)d_out, nullptr, NM, NE, NE);
}